// Round 1
// baseline (330.299 us; speedup 1.0000x reference)
//
#include <hip/hip_runtime.h>
#include <hip/hip_bf16.h>

// ---------- types ----------
typedef __attribute__((ext_vector_type(8))) short short8;   // 8 x bf16 bits
typedef __attribute__((ext_vector_type(4))) float f32x4;

#define P72 72    // bf16 tile pitch (ushorts): 144B rows, 16B-aligned

__device__ __forceinline__ unsigned short f2bf(float f) {
    union { float f; unsigned int u; } v; v.f = f;
    unsigned int r = (v.u + 0x7FFFu + ((v.u >> 16) & 1u)) >> 16;
    return (unsigned short)r;
}
__device__ __forceinline__ float bf2f(unsigned short b) {
    union { unsigned int u; float f; } v; v.u = ((unsigned int)b) << 16; return v.f;
}

#define WAVE_SYNC() do { __asm__ volatile("s_waitcnt lgkmcnt(0)" ::: "memory"); \
                         __builtin_amdgcn_sched_barrier(0); } while (0)

// block barrier WITHOUT vmcnt drain: LDS visibility only (stores keep draining
// in background — keeps fire-and-forget global stores off the serial chain)
#define LGKM_BARRIER() do { __asm__ volatile("s_waitcnt lgkmcnt(0)" ::: "memory"); \
                            __builtin_amdgcn_s_barrier(); \
                            __builtin_amdgcn_sched_barrier(0); } while (0)

#define ASYNC16(G, L) __builtin_amdgcn_global_load_lds( \
    (const __attribute__((address_space(1))) void*)(G), \
    (__attribute__((address_space(3))) void*)(L), 16, 0, 0)

// ---------- fused LayerNorm (blocks 0..8191) + w_qkvb transpose (8192..12287) ----------
__global__ __launch_bounds__(256) void ln_wqt_kernel(
    const float* __restrict__ x, const float* __restrict__ g,
    const float* __restrict__ bv_, unsigned short* __restrict__ out,
    const float* __restrict__ w_qkvb, unsigned short* __restrict__ WQT)
{
    __shared__ float pool[32 * 33];
    const int tid = threadIdx.x;
    if (blockIdx.x < 8192) {
        const int row = blockIdx.x;
        const float4 v = ((const float4*)(x + (size_t)row * 1024))[tid];
        float s  = v.x + v.y + v.z + v.w;
        float s2 = v.x * v.x + v.y * v.y + v.z * v.z + v.w * v.w;
#pragma unroll
        for (int off = 1; off < 64; off <<= 1) {
            s  += __shfl_xor(s, off);
            s2 += __shfl_xor(s2, off);
        }
        const int wv = tid >> 6;
        if ((tid & 63) == 0) { pool[wv] = s; pool[4 + wv] = s2; }
        __syncthreads();
        s  = pool[0] + pool[1] + pool[2] + pool[3];
        s2 = pool[4] + pool[5] + pool[6] + pool[7];
        const float mu  = s * (1.0f / 1024.0f);
        const float var = s2 * (1.0f / 1024.0f) - mu * mu;
        const float inv = rsqrtf(var + 1e-5f);
        const float4 gv = ((const float4*)g)[tid];
        const float4 bb = ((const float4*)bv_)[tid];
        ushort4 o;
        o.x = f2bf((v.x - mu) * inv * gv.x + bb.x);
        o.y = f2bf((v.y - mu) * inv * gv.y + bb.y);
        o.z = f2bf((v.z - mu) * inv * gv.z + bb.z);
        o.w = f2bf((v.w - mu) * inv * gv.w + bb.w);
        *(ushort4*)(out + (size_t)row * 1024 + tid * 4) = o;
    } else {
        // transpose f32 w_qkvb[1024][4096] -> bf16 WQT[4096][1024]
        const int blk = blockIdx.x - 8192;
        const int c0 = (blk & 127) * 32, r0 = (blk >> 7) * 32;
        const int tx = tid & 31, ty = tid >> 5;   // 32 x 8
#pragma unroll
        for (int yy = 0; yy < 32; yy += 8)
            pool[(ty + yy) * 33 + tx] = w_qkvb[(size_t)(r0 + ty + yy) * 4096 + c0 + tx];
        __syncthreads();
#pragma unroll
        for (int yy = 0; yy < 32; yy += 8)
            WQT[(size_t)(c0 + ty + yy) * 1024 + r0 + tx] = f2bf(pool[tx * 33 + ty + yy]);
    }
}

// ---------- 128x128 MFMA GEMM — 3-buffer, counted vmcnt(8), XCD-swizzled ----------
// (still used for the output projection, mode 1)
__global__ __launch_bounds__(256) void gemm128(
    const unsigned short* __restrict__ A, const unsigned short* __restrict__ Bt,
    const float* __restrict__ bias, int K, int N, int mode, int n0_off,
    const float* __restrict__ resid, float* __restrict__ outf,
    unsigned short* __restrict__ qo, unsigned short* __restrict__ ko,
    unsigned short* __restrict__ vo, unsigned short* __restrict__ bo)
{
    __shared__ __align__(16) unsigned short SMEM[24576];  // 48KB
    const int tid = threadIdx.x;
    // T1: bijective XCD swizzle — each XCD gets a contiguous tile range
    const int nwg = (int)(gridDim.x * gridDim.y);
    const int flat = (int)(blockIdx.y * gridDim.x + blockIdx.x);
    const int id2 = (flat & 7) * (nwg >> 3) + (flat >> 3);
    const int M0 = (id2 / (int)gridDim.x) * 128;
    const int N0 = (id2 % (int)gridDim.x) * 128 + n0_off;
    const int lane = tid & 63;
    const int w = tid >> 6, wr = w >> 1, wc = w & 1;
    const int r15 = lane & 15, kg = lane >> 4;
    const int lr = lane >> 2, lc = (lane & 3) * 8;

    const unsigned short* Arow0 = A  + (size_t)(M0 + w * 16 + lr) * K + lc;
    const unsigned short* Arow1 = A  + (size_t)(M0 + 64 + w * 16 + lr) * K + lc;
    const unsigned short* Brow0 = Bt + (size_t)(N0 + w * 16 + lr) * K + lc;
    const unsigned short* Brow1 = Bt + (size_t)(N0 + 64 + w * 16 + lr) * K + lc;

    f32x4 acc[4][4] = {};

    ASYNC16(Arow0, &SMEM[(w * 16) * 32]);
    ASYNC16(Arow1, &SMEM[(64 + w * 16) * 32]);
    ASYNC16(Brow0, &SMEM[12288 + (w * 16) * 32]);
    ASYNC16(Brow1, &SMEM[12288 + (64 + w * 16) * 32]);
    if (32 < K) {
        ASYNC16(Arow0 + 32, &SMEM[4096 + (w * 16) * 32]);
        ASYNC16(Arow1 + 32, &SMEM[4096 + (64 + w * 16) * 32]);
        ASYNC16(Brow0 + 32, &SMEM[12288 + 4096 + (w * 16) * 32]);
        ASYNC16(Brow1 + 32, &SMEM[12288 + 4096 + (64 + w * 16) * 32]);
    }

    int cur = 0;
    for (int k0 = 0; k0 < K; k0 += 32) {
        if (k0 + 64 < K) {
            int n2 = cur + 2; if (n2 >= 3) n2 -= 3;
            const int nb = n2 * 4096;
            ASYNC16(Arow0 + k0 + 64, &SMEM[nb + (w * 16) * 32]);
            ASYNC16(Arow1 + k0 + 64, &SMEM[nb + (64 + w * 16) * 32]);
            ASYNC16(Brow0 + k0 + 64, &SMEM[12288 + nb + (w * 16) * 32]);
            ASYNC16(Brow1 + k0 + 64, &SMEM[12288 + nb + (64 + w * 16) * 32]);
            __asm__ volatile("s_waitcnt vmcnt(8)" ::: "memory");
        } else if (k0 + 32 < K) {
            __asm__ volatile("s_waitcnt vmcnt(4)" ::: "memory");
        } else {
            __asm__ volatile("s_waitcnt vmcnt(0)" ::: "memory");
        }
        __builtin_amdgcn_s_barrier();
        __builtin_amdgcn_sched_barrier(0);
        const int cb = cur * 4096;
        short8 af[4], bf[4];
#pragma unroll
        for (int m = 0; m < 4; m++)
            af[m] = *(const short8*)&SMEM[cb + (wr * 64 + m * 16 + r15) * 32 + kg * 8];
#pragma unroll
        for (int n = 0; n < 4; n++)
            bf[n] = *(const short8*)&SMEM[12288 + cb + (wc * 64 + n * 16 + r15) * 32 + kg * 8];
#pragma unroll
        for (int m = 0; m < 4; m++)
#pragma unroll
            for (int n = 0; n < 4; n++)
                acc[m][n] = __builtin_amdgcn_mfma_f32_16x16x32_bf16(af[m], bf[n], acc[m][n], 0, 0, 0);
        __builtin_amdgcn_sched_barrier(0);
        __builtin_amdgcn_s_barrier();
        cur += 1; if (cur >= 3) cur = 0;
    }

    float bias_r[4];
#pragma unroll
    for (int n = 0; n < 4; n++) bias_r[n] = bias[N0 + wc * 64 + n * 16 + r15];

    if (mode == 0) {
        const int sec = N0 >> 10;
        const int hA = (N0 & 1023) >> 6;
        unsigned short* arr = (sec == 0) ? qo : (sec == 1) ? ko : (sec == 2) ? vo : bo;
#pragma unroll
        for (int p = 0; p < 2; ++p) {
            __syncthreads();
            if (wr == p) {
#pragma unroll
                for (int m = 0; m < 4; m++)
#pragma unroll
                    for (int n = 0; n < 4; n++)
#pragma unroll
                        for (int j = 0; j < 4; j++) {
                            float val = acc[m][n][j] + bias_r[n];
                            if (sec == 3) val = 1.0f / (1.0f + expf(-val));
                            SMEM[(m * 16 + kg * 4 + j) * 136 + wc * 64 + n * 16 + r15] = f2bf(val);
                        }
            }
            __syncthreads();
            const int tl = tid >> 2, sg = tid & 3;
            const int gm = M0 + p * 64 + tl;
            const int b = gm >> 11, t = gm & 2047;
            const int h = hA + (sg >> 1), d0 = (sg & 1) * 32;
            const int colbase = sg * 32;
            const size_t dst = ((size_t)(b * 16 + h) * 2048 + t) * 64 + d0;
#pragma unroll
            for (int i = 0; i < 4; i++) {
                uint4 v = *(const uint4*)&SMEM[tl * 136 + colbase + i * 8];
                *(uint4*)(arr + dst + i * 8) = v;
            }
        }
    } else {
        float* stf = (float*)SMEM;
#pragma unroll
        for (int p = 0; p < 4; ++p) {
            __syncthreads();
            if (wr == (p >> 1)) {
#pragma unroll
                for (int mm = 0; mm < 2; mm++)
#pragma unroll
                    for (int n = 0; n < 4; n++)
#pragma unroll
                        for (int j = 0; j < 4; j++)
                            stf[(mm * 16 + kg * 4 + j) * 132 + wc * 64 + n * 16 + r15] =
                                acc[(p & 1) * 2 + mm][n][j] + bias_r[n];
            }
            __syncthreads();
            const int rl = tid >> 3, sg = (tid & 7) * 16;
            const size_t rowo = (size_t)(M0 + p * 32 + rl) * N + N0 + sg;
#pragma unroll
            for (int i = 0; i < 4; i++) {
                float4 v = *(const float4*)&stf[rl * 132 + sg + i * 4];
                float4 r = *(const float4*)(resid + rowo + i * 4);
                v.x += r.x; v.y += r.y; v.z += r.z; v.w += r.w;
                *(float4*)(outf + rowo + i * 4) = v;
            }
        }
    }
}

// ---------- 256x128 phase-interleaved MFMA GEMM (T2+T3+T4+T5) for the QKVB proj ----
// 512 threads = 8 waves (2M x 4N), BK=64, 3 LDS buffers (144KB), counted vmcnt(6).
// LDS tiles XOR-swizzled: chunk' = chunk ^ (row&7)  (involution; applied on the
// pre-swizzled global source since global_load_lds writes linearly, and on reads).
// Grid: x = N/128 tiles, y = M/256 tiles; nwg % 8 == 0 required (768 is).
__global__ __launch_bounds__(512, 2) void gemm256(
    const unsigned short* __restrict__ A, const unsigned short* __restrict__ Bt,
    const float* __restrict__ bias, int K, int n0_off,
    unsigned short* __restrict__ qo, unsigned short* __restrict__ ko,
    unsigned short* __restrict__ vo, unsigned short* __restrict__ bo)
{
    __shared__ __align__(16) unsigned short SMEM[73728];   // 144KB: 3 x (A 32KB + B 16KB)
    const int tid = threadIdx.x;
    const int nwg = (int)(gridDim.x * gridDim.y);
    const int flat = (int)(blockIdx.y * gridDim.x + blockIdx.x);
    const int id2 = (flat & 7) * (nwg >> 3) + (flat >> 3);
    const int M0 = (id2 / (int)gridDim.x) * 256;
    const int N0 = (id2 % (int)gridDim.x) * 128 + n0_off;

    const int lane = tid & 63, wv = tid >> 6;
    const int wr = wv >> 2, wc = wv & 3;           // wave grid 2 (M) x 4 (N)
    const int r15 = lane & 15, kg = lane >> 4;
    const int swz = r15 & 7;                       // read-side XOR (row&7 == r15&7)

    // staging source: lane covers (row = 8i + l>>3, stored chunk = l&7) which must
    // hold global chunk (l&7) ^ (l>>3)   [8 chunks of 16B per 128B row]
    const int srow = lane >> 3;
    const int schk = (lane & 7) ^ srow;
    const unsigned short* Asrc = A  + (size_t)(M0 + wv * 8 + srow) * K + schk * 8;
    const unsigned short* Bsrc = Bt + (size_t)(N0 + wv * 8 + srow) * K + schk * 8;

    // bias first: its 2 vmem ops are oldest, drain before any counted wait matters
    float bias_r[2];
    bias_r[0] = bias[N0 + wc * 32 + r15];
    bias_r[1] = bias[N0 + wc * 32 + 16 + r15];
    __builtin_amdgcn_sched_barrier(0);

    auto stageA = [&](int b_, int ko_, int i_) {
        ASYNC16(Asrc + (size_t)i_ * 64 * K + ko_,
                &SMEM[b_ * 24576 + (i_ * 64 + wv * 8) * 64]);
    };
    auto stageB = [&](int b_, int ko_, int i_) {
        ASYNC16(Bsrc + (size_t)i_ * 64 * K + ko_,
                &SMEM[b_ * 24576 + 16384 + (i_ * 64 + wv * 8) * 64]);
    };

    // prologue: stage K-tiles 0 and 1 (6 ops each: A i=0..3, B i=0..1)
#pragma unroll
    for (int i = 0; i < 4; i++) stageA(0, 0, i);
    stageB(0, 0, 0); stageB(0, 0, 1);
#pragma unroll
    for (int i = 0; i < 4; i++) stageA(1, 64, i);
    stageB(1, 64, 0); stageB(1, 64, 1);

    f32x4 acc[8][2] = {};

#define PH_PRE() do { __builtin_amdgcn_s_barrier(); \
                      __asm__ volatile("s_waitcnt lgkmcnt(0)" ::: "memory"); \
                      __builtin_amdgcn_sched_barrier(0); \
                      __builtin_amdgcn_s_setprio(1); } while (0)
#define PH_POST() do { __builtin_amdgcn_s_setprio(0); \
                       __builtin_amdgcn_sched_barrier(0); \
                       __builtin_amdgcn_s_barrier(); } while (0)

    const int NT = K >> 6;
    int cur = 0;
    for (int t = 0; t < NT; ++t) {
        // tile-top: drain this tile's 6 stage ops, leave the next tile's in flight
        if (t + 1 < NT) { __asm__ volatile("s_waitcnt vmcnt(6)" ::: "memory"); }
        else            { __asm__ volatile("s_waitcnt vmcnt(0)" ::: "memory"); }
        __builtin_amdgcn_s_barrier();
        __builtin_amdgcn_sched_barrier(0);

        const unsigned short* Ab = &SMEM[cur * 24576];
        const unsigned short* Bb = &SMEM[cur * 24576 + 16384];
        int nb = cur + 2; if (nb >= 3) nb -= 3;
        const int nko = (t + 2) * 64;
        const bool pf = (t + 2 < NT);

        short8 af[4], bf[2];
        // ---- phase 0: ks=0, m=0..3 (B n=0..1 read here, reused in phase 1) ----
#pragma unroll
        for (int m = 0; m < 4; m++)
            af[m] = *(const short8*)&Ab[(wr * 128 + m * 16 + r15) * 64 + (kg ^ swz) * 8];
#pragma unroll
        for (int n = 0; n < 2; n++)
            bf[n] = *(const short8*)&Bb[(wc * 32 + n * 16 + r15) * 64 + (kg ^ swz) * 8];
        if (pf) { stageA(nb, nko, 0); stageA(nb, nko, 1); }
        PH_PRE();
#pragma unroll
        for (int m = 0; m < 4; m++)
#pragma unroll
            for (int n = 0; n < 2; n++)
                acc[m][n] = __builtin_amdgcn_mfma_f32_16x16x32_bf16(af[m], bf[n], acc[m][n], 0, 0, 0);
        PH_POST();
        // ---- phase 1: ks=0, m=4..7 ----
#pragma unroll
        for (int m = 0; m < 4; m++)
            af[m] = *(const short8*)&Ab[(wr * 128 + (m + 4) * 16 + r15) * 64 + (kg ^ swz) * 8];
        if (pf) { stageA(nb, nko, 2); stageA(nb, nko, 3); }
        PH_PRE();
#pragma unroll
        for (int m = 0; m < 4; m++)
#pragma unroll
            for (int n = 0; n < 2; n++)
                acc[m + 4][n] = __builtin_amdgcn_mfma_f32_16x16x32_bf16(af[m], bf[n], acc[m + 4][n], 0, 0, 0);
        PH_POST();
        // ---- phase 2: ks=1, m=0..3 ----
#pragma unroll
        for (int m = 0; m < 4; m++)
            af[m] = *(const short8*)&Ab[(wr * 128 + m * 16 + r15) * 64 + ((4 + kg) ^ swz) * 8];
#pragma unroll
        for (int n = 0; n < 2; n++)
            bf[n] = *(const short8*)&Bb[(wc * 32 + n * 16 + r15) * 64 + ((4 + kg) ^ swz) * 8];
        if (pf) { stageB(nb, nko, 0); stageB(nb, nko, 1); }
        PH_PRE();
#pragma unroll
        for (int m = 0; m < 4; m++)
#pragma unroll
            for (int n = 0; n < 2; n++)
                acc[m][n] = __builtin_amdgcn_mfma_f32_16x16x32_bf16(af[m], bf[n], acc[m][n], 0, 0, 0);
        PH_POST();
        // ---- phase 3: ks=1, m=4..7 (no trailing barrier: tile-top covers it) ----
#pragma unroll
        for (int m = 0; m < 4; m++)
            af[m] = *(const short8*)&Ab[(wr * 128 + (m + 4) * 16 + r15) * 64 + ((4 + kg) ^ swz) * 8];
        PH_PRE();
#pragma unroll
        for (int m = 0; m < 4; m++)
#pragma unroll
            for (int n = 0; n < 2; n++)
                acc[m + 4][n] = __builtin_amdgcn_mfma_f32_16x16x32_bf16(af[m], bf[n], acc[m + 4][n], 0, 0, 0);
        __builtin_amdgcn_s_setprio(0);
        __builtin_amdgcn_sched_barrier(0);

        cur += 1; if (cur >= 3) cur = 0;
    }
#undef PH_PRE
#undef PH_POST

    // ---- epilogue: stage bf16 via LDS, scatter to per-head [b,h,t,d] layout ----
    const int sec = N0 >> 10;
    const int hA = (N0 & 1023) >> 6;
    unsigned short* arr = (sec == 0) ? qo : (sec == 1) ? ko : (sec == 2) ? vo : bo;
#pragma unroll
    for (int p = 0; p < 2; ++p) {
        __syncthreads();
        if (wr == p) {
#pragma unroll
            for (int m = 0; m < 8; m++)
#pragma unroll
                for (int n = 0; n < 2; n++)
#pragma unroll
                    for (int j = 0; j < 4; j++) {
                        float val = acc[m][n][j] + bias_r[n];
                        if (sec == 3) val = 1.0f / (1.0f + expf(-val));
                        SMEM[(m * 16 + kg * 4 + j) * 136 + wc * 32 + n * 16 + r15] = f2bf(val);
                    }
        }
        __syncthreads();
        const int row = tid >> 2, sg = tid & 3;
        const int gm = M0 + p * 128 + row;
        const int b = gm >> 11, tt = gm & 2047;
        const int h = hA + (sg >> 1), d0 = (sg & 1) * 32;
        const size_t dst = ((size_t)(b * 16 + h) * 2048 + tt) * 64 + d0;
#pragma unroll
        for (int i = 0; i < 4; i++) {
            uint4 v = *(const uint4*)&SMEM[row * 136 + sg * 32 + i * 8];
            *(uint4*)(arr + dst + i * 8) = v;
        }
    }
}

// ---------- prep: normalize K; A0=tril_strict(KK^T) bf16; A0D f32 diag blocks;
//            KT, VT, BT transposes.  grid 2048 = bh*32 + c ----------
__global__ __launch_bounds__(256) void prep_kernel(
    const unsigned short* __restrict__ Kpre, const unsigned short* __restrict__ Vin,
    const unsigned short* __restrict__ Bin,
    unsigned short* __restrict__ Kb, unsigned short* __restrict__ A0g,
    float* __restrict__ A0Dg, unsigned short* __restrict__ KTg,
    unsigned short* __restrict__ VTg, unsigned short* __restrict__ BTg)
{
    __shared__ __align__(16) unsigned short Ks[64 * P72];
    __shared__ __align__(16) unsigned short Vs[64 * P72];
    __shared__ __align__(16) unsigned short Bs[64 * P72];
    __shared__ __align__(16) unsigned short Os[64 * P72];
    const int cid = blockIdx.x, tid = threadIdx.x;
    const size_t gbase = (size_t)cid * 4096;
    const int r0 = tid >> 2, c0 = (tid & 3) * 16;
    {
        uint4 k0 = *(const uint4*)(Kpre + gbase + r0 * 64 + c0), k1 = *(const uint4*)(Kpre + gbase + r0 * 64 + c0 + 8);
        uint4 v0 = *(const uint4*)(Vin + gbase + r0 * 64 + c0),  v1 = *(const uint4*)(Vin + gbase + r0 * 64 + c0 + 8);
        uint4 b0 = *(const uint4*)(Bin + gbase + r0 * 64 + c0),  b1 = *(const uint4*)(Bin + gbase + r0 * 64 + c0 + 8);
        *(uint4*)&Ks[r0 * P72 + c0] = k0; *(uint4*)&Ks[r0 * P72 + c0 + 8] = k1;
        *(uint4*)&Vs[r0 * P72 + c0] = v0; *(uint4*)&Vs[r0 * P72 + c0 + 8] = v1;
        *(uint4*)&Bs[r0 * P72 + c0] = b0; *(uint4*)&Bs[r0 * P72 + c0 + 8] = b1;
    }
    __syncthreads();
    {
        const int row = tid >> 2, seg = tid & 3;
        float v[16]; float ss = 0.f;
#pragma unroll
        for (int q = 0; q < 16; q++) { v[q] = bf2f(Ks[row * P72 + seg * 16 + q]); ss = fmaf(v[q], v[q], ss); }
        ss += __shfl_xor(ss, 1); ss += __shfl_xor(ss, 2);
        const float inv = 1.0f / fmaxf(sqrtf(ss), 1e-6f);
        unsigned short t16[16];
#pragma unroll
        for (int q = 0; q < 16; q++) t16[q] = f2bf(v[q] * inv);
        *(uint4*)&Ks[row * P72 + seg * 16]     = *(uint4*)&t16[0];
        *(uint4*)&Ks[row * P72 + seg * 16 + 8] = *(uint4*)&t16[8];
        *(uint4*)(Kb + gbase + row * 64 + seg * 16)     = *(uint4*)&t16[0];
        *(uint4*)(Kb + gbase + row * 64 + seg * 16 + 8) = *(uint4*)&t16[8];
    }
    __syncthreads();
    const int lane = tid & 63, w = tid >> 6;
    const int r15 = lane & 15, kg = lane >> 4;
    f32x4 acc[4] = {{0,0,0,0},{0,0,0,0},{0,0,0,0},{0,0,0,0}};
#pragma unroll
    for (int ks = 0; ks < 2; ks++) {
        short8 afr = *(const short8*)&Ks[(w * 16 + r15) * P72 + ks * 32 + kg * 8];
#pragma unroll
        for (int n = 0; n < 4; n++) {
            short8 bfr = *(const short8*)&Ks[(n * 16 + r15) * P72 + ks * 32 + kg * 8];
            acc[n] = __builtin_amdgcn_mfma_f32_16x16x32_bf16(afr, bfr, acc[n], 0, 0, 0);
        }
    }
#pragma unroll
    for (int n = 0; n < 4; n++) {
#pragma unroll
        for (int j = 0; j < 4; j++) {
            const int s = w * 16 + kg * 4 + j, r = n * 16 + r15;
            Os[s * P72 + r] = (r < s) ? f2bf(acc[n][j]) : (unsigned short)0;
        }
        if (n == w) {
            float4 d;
            d.x = (r15 < kg * 4 + 0) ? acc[n][0] : 0.f;
            d.y = (r15 < kg * 4 + 1) ? acc[n][1] : 0.f;
            d.z = (r15 < kg * 4 + 2) ? acc[n][2] : 0.f;
            d.w = (r15 < kg * 4 + 3) ? acc[n][3] : 0.f;
            *(float4*)(A0Dg + (size_t)cid * 1024 + w * 256 + r15 * 16 + kg * 4) = d;
        }
    }
    __syncthreads();
    {
        uint4 x0 = *(const uint4*)&Os[r0 * P72 + c0];
        uint4 x1 = *(const uint4*)&Os[r0 * P72 + c0 + 8];
        *(uint4*)(A0g + gbase + r0 * 64 + c0) = x0;
        *(uint4*)(A0g + gbase + r0 * 64 + c0 + 8) = x1;
    }
    {
        const int d = tid >> 2, s0 = (tid & 3) * 16;
        unsigned short tk[16], tv[16], tb[16];
#pragma unroll
        for (int k = 0; k < 16; k++) {
            tk[k] = Ks[(s0 + k) * P72 + d];
            tv[k] = Vs[(s0 + k) * P72 + d];
            tb[k] = Bs[(s0 + k) * P72 + d];
        }
        *(uint4*)(KTg + gbase + (size_t)d * 64 + s0)     = *(uint4*)&tk[0];
        *(uint4*)(KTg + gbase + (size_t)d * 64 + s0 + 8) = *(uint4*)&tk[8];
        *(uint4*)(VTg + gbase + (size_t)d * 64 + s0)     = *(uint4*)&tv[0];
        *(uint4*)(VTg + gbase + (size_t)d * 64 + s0 + 8) = *(uint4*)&tv[8];
        *(uint4*)(BTg + gbase + (size_t)d * 64 + s0)     = *(uint4*)&tb[0];
        *(uint4*)(BTg + gbase + (size_t)d * 64 + s0 + 8) = *(uint4*)&tb[8];
    }
}

// ---------- fused: blocks 0-63 = serial scan; 64-575 = Q-GEMM; 576-1599 = WOT ----------
__global__ __launch_bounds__(256, 1) void fused_scan_kernel(
    const unsigned short* __restrict__ A0g, const unsigned short* __restrict__ Kb,
    const unsigned short* __restrict__ KTg, const float* __restrict__ A0Dg,
    const unsigned short* __restrict__ VTg, const unsigned short* __restrict__ BTg,
    unsigned short* __restrict__ Scg, unsigned short* __restrict__ UTg,
    const unsigned short* __restrict__ NORM, const unsigned short* __restrict__ WQT,
    const float* __restrict__ bias, unsigned short* __restrict__ qo,
    const float* __restrict__ w_out, unsigned short* __restrict__ WOT)
{
    __shared__ __align__(16) unsigned char POOL[120832];
    unsigned short* us = (unsigned short*)POOL;
    const int tid = threadIdx.x;

    if (blockIdx.x < 64) {
        unsigned short* sK  = us;            // [2][4608]
        unsigned short* sKT = us + 9216;
        unsigned short* sA0 = us + 18432;
        unsigned short* sVT = us + 27648;
        unsigned short* sBT = us + 36864;
        float* sA0D = (float*)(POOL + 92160);  // [2][1280]
        unsigned short* Sbf = us + 51200;      // [4608]
        unsigned short* UTs = us + 55808;      // [4608]

        const int bh = blockIdx.x;
        const int lane = tid & 63, w = tid >> 6;
        const int r15 = lane & 15, kg = lane >> 4;
        const int sr = tid >> 2, sc = (tid & 3) * 16;
        const int qr = 16 * w + (lane >> 2), qc = (lane & 3) * 16;
        const size_t base0 = (size_t)bh * 32 * 4096;
        const size_t baseD = (size_t)bh * 32 * 1024;
        const int dOff = (w * 16 + (sr & 15)) * 20 + (tid & 3) * 4;

        f32x4 Sreg[4] = {};
        uint4 g[10]; float4 gD;

        const uint4 z4 = {0u, 0u, 0u, 0u};
        *(uint4*)&Sbf[sr * P72 + sc] = z4;
        *(uint4*)&Sbf[sr * P72 + sc + 8] = z4;
        {
            const size_t gb = base0 + sr * 64 + sc;
            g[0] = *(const uint4*)(Kb  + gb); g[1] = *(const uint4*)(Kb  + gb + 8);
            g[2] = *(const uint4*)(KTg + gb); g[3] = *(const uint4*)(KTg + gb + 8);
            g[4] = *(const uint4*)(A0g + gb); g[5] = *(const uint4*)(A0g + gb + 8);
            g[6] = *(const uint4*)(VTg + gb); g[7] = *(const uint4*)(VTg + gb + 8);
            g[8] = *(const uint4*)(BTg + gb); g[9] = *(const uint4*)(BTg + gb + 8);
            gD   = *(const float4*)(A0Dg + baseD + tid * 4);
            *(uint4*)&sK [sr * P72 + sc] = g[0]; *(uint4*)&sK [sr * P72 + sc + 8] = g[1];
            *(uint4*)&sKT[sr * P72 + sc] = g[2]; *(uint4*)&sKT[sr * P72 + sc + 8] = g[3];
            *(uint4*)&sA0[sr * P72 + sc] = g[4]; *(uint4*)&sA0[sr * P72 + sc + 8] = g[5];
            *(uint4*)&sVT[sr * P72 + sc] = g[6]; *(uint4*)&sVT[sr * P72 + sc + 8] = g[7];
            *(uint4*)&sBT[sr * P72 + sc] = g[8]; *(uint4*)&sBT[sr * P72 + sc + 8] = g[9];
            *(float4*)&sA0D[dOff] = gD;
        }

#pragma unroll 1
        for (int c = 0; c < 32; ++c) {
            const int cur = c & 1, nxt = cur ^ 1;
            LGKM_BARRIER();   // LDS visibility only; global stores drain in background
            if (c < 31) {
                const size_t gb = base0 + (size_t)(c + 1) * 4096 + sr * 64 + sc;
                g[0] = *(const uint4*)(Kb  + gb); g[1] = *(const uint4*)(Kb  + gb + 8);
                g[2] = *(const uint4*)(KTg + gb); g[3] = *(const uint4*)(KTg + gb + 8);
                g[4] = *(const uint4*)(A0g + gb); g[5] = *(const uint4*)(A0g + gb + 8);
                g[6] = *(const uint4*)(VTg + gb); g[7] = *(const uint4*)(VTg + gb + 8);
                g[8] = *(const uint4*)(BTg + gb); g[9] = *(const uint4*)(BTg + gb + 8);
                gD   = *(const float4*)(A0Dg + baseD + (size_t)(c + 1) * 1024 + tid * 4);
            }
            const unsigned short* KsC  = &sK [cur * 4608];
            const unsigned short* KTsC = &sKT[cur * 4608];
            const unsigned short* A0C  = &sA0[cur * 4608];
            const unsigned short* VTC  = &sVT[cur * 4608];
            const unsigned short* BTC  = &sBT[cur * 4608];
            const float*          A0DC = &sA0D[cur * 1280];

            *(uint4*)&UTs[(16 * w + r15) * P72 + kg * 16] = z4;
            *(uint4*)&UTs[(16 * w + r15) * P72 + kg * 16 + 8] = z4;

            {   // snapshot Scg = +S
                uint4 a = *(const uint4*)&Sbf[qr * P72 + qc];
                uint4 b2 = *(const uint4*)&Sbf[qr * P72 + qc + 8];
                const unsigned FL = 0x80008000u;
                a.x ^= FL; a.y ^= FL; a.z ^= FL; a.w ^= FL;
                b2.x ^= FL; b2.y ^= FL; b2.z ^= FL; b2.w ^= FL;
                const size_t so = base0 + (size_t)c * 4096 + qr * 64 + qc;
                *(uint4*)(Scg + so) = a;
                *(uint4*)(Scg + so + 8) = b2;
            }

            f32x4 y[4];
#pragma unroll
            for (int st = 0; st < 4; st++) {
                ushort4 vv = *(const ushort4*)&VTC[(16 * w + r15) * P72 + st * 16 + kg * 4];
                y[st][0] = bf2f(vv.x); y[st][1] = bf2f(vv.y);
                y[st][2] = bf2f(vv.z); y[st][3] = bf2f(vv.w);
            }
#pragma unroll
            for (int ks = 0; ks < 2; ks++) {
                short8 bfr = *(const short8*)&Sbf[(16 * w + r15) * P72 + ks * 32 + kg * 8];
#pragma unroll
                for (int st = 0; st < 4; st++) {
                    short8 afr = *(const short8*)&KsC[(st * 16 + r15) * P72 + ks * 32 + kg * 8];
                    y[st] = __builtin_amdgcn_mfma_f32_16x16x32_bf16(afr, bfr, y[st], 0, 0, 0);
                }
            }

#pragma unroll
            for (int b = 0; b < 4; b++) {
                if (b > 0) {
                    WAVE_SYNC();
                    f32x4 corr = {};
                    {
                        short8 afr = *(const short8*)&A0C[(b * 16 + r15) * P72 + kg * 8];
                        short8 bfr = *(const short8*)&UTs[(16 * w + r15) * P72 + kg * 8];
                        corr = __builtin_amdgcn_mfma_f32_16x16x32_bf16(afr, bfr, corr, 0, 0, 0);
                    }
                    if (b == 3) {
                        short8 afr = *(const short8*)&A0C[(b * 16 + r15) * P72 + 32 + kg * 8];
                        short8 bfr = *(const short8*)&UTs[(16 * w + r15) * P72 + 32 + kg * 8];
                        corr = __builtin_amdgcn_mfma_f32_16x16x32_bf16(afr, bfr, corr, 0, 0, 0);
                    }
                    y[b] = y[b] - corr;
                }
                ushort4 bt4 = *(const ushort4*)&BTC[(16 * w + r15) * P72 + b * 16 + kg * 4];
                const float bta0 = bf2f(bt4.x), bta1 = bf2f(bt4.y);
                const float bta2 = bf2f(bt4.z), bta3 = bf2f(bt4.w);
                float us0 = 0.f, us1 = 0.f, us2 = 0.f, us3 = 0.f;
#pragma unroll
                for (int own = 0; own < 4; own++) {
                    const f32x4 c40 = *(const f32x4*)&A0DC[(b * 16 + own * 4 + 0) * 20 + kg * 4];
                    const f32x4 c41 = *(const f32x4*)&A0DC[(b * 16 + own * 4 + 1) * 20 + kg * 4];
                    const f32x4 c42 = *(const f32x4*)&A0DC[(b * 16 + own * 4 + 2) * 20 + kg * 4];
                    const f32x4 c43 = *(const f32x4*)&A0DC[(b * 16 + own * 4 + 3) * 20 + kg * 4];
                    if (kg == own) {
                        us0 = bta0 * y[b][0];
                        us1 = bta1 * (y[b][1] - c40[1] * us0);
                        us2 = bta2 * (y[b][2] - c40[2] * us0 - c41[2] * us1);
                        us3 = bta3 * (y[b][3] - c40[3] * us0 - c41[3] * us1 - c42[3] * us2);
                    }
                    const int src = own * 16 + r15;
                    const float u0 = __shfl(us0, src), u1 = __shfl(us1, src);
                    const float u2 = __shfl(us2, src), u3 = __shfl(us3, src);
                    if (kg > own)
                        y[b] = y[b] - (c40 * u0 + c41 * u1 + c42 * u2 + c43 * u3);
                }
                ushort4 up;
                up.x = f2bf(us0); up.y = f2bf(us1); up.z = f2bf(us2); up.w = f2bf(us3);
                *(ushort4*)&UTs[(16 * w + r15) * P72 + b * 16 + kg * 4] = up;
            }
            WAVE_SYNC();

            {
                uint4 a = *(const uint4*)&UTs[qr * P72 + qc];
                uint4 b2 = *(const uint4*)&UTs[qr * P72 + qc + 8];
                const size_t so = base0 + (size_t)c * 4096 + qr * 64 + qc;
                *(uint4*)(UTg + so) = a;
                *(uint4*)(UTg + so + 8) = b2;
            }

#pragma unroll
            for (int ks = 0; ks < 2; ks++) {
                short8 afr = *(const short8*)&UTs[(16 * w + r15) * P72 + ks * 32 + kg * 8];
#pragma unroll
                for (int n = 0; n < 4; n++) {
                    short8 bfr = *(const short8*)&KTsC[(n * 16 + r15) * P72 + ks * 32 + kg * 8];
                    Sreg[n] = __builtin_amdgcn_mfma_f32_16x16x32_bf16(afr, bfr, Sreg[n], 0, 0, 0);
                }
            }
#pragma unroll
            for (int n = 0; n < 4; n++)
#pragma unroll
                for (int jj = 0; jj < 4; jj++)
                    Sbf[(16 * w + kg * 4 + jj) * P72 + n * 16 + r15] = f2bf(-Sreg[n][jj]);

            if (c < 31) {
                *(uint4*)&sK [nxt * 4608 + sr * P72 + sc] = g[0]; *(uint4*)&sK [nxt * 4608 + sr * P72 + sc + 8] = g[1];
                *(uint4*)&sKT[nxt * 4608 + sr * P72 + sc] = g[2]; *(uint4*)&sKT[nxt * 4608 + sr * P72 + sc + 8] = g[3];
                *(uint4*)&sA0[nxt * 4608 + sr * P72 + sc] = g[4]; *(uint4*)&sA0[nxt * 4608 + sr * P72 + sc + 8] = g[5];
                *(uint4*)&sVT[nxt * 4608 + sr * P72 + sc] = g[6]; *(uint4*)&sVT[nxt * 4608 + sr * P72 + sc + 8] = g[7];
                *(uint4*)&sBT[nxt * 4608 + sr * P72 + sc] = g[8]; *(uint4*)&sBT[nxt * 4608 + sr * P72 + sc + 8] = g[9];
                *(float4*)&sA0D[nxt * 1280 + dOff] = gD;
            }
        }
    } else if (blockIdx.x < 64 + 512) {
        // ======== Q-GEMM: NORM[8192][1024] x WQT[0:1024][1024]^T -> qo ========
        unsigned short* SMEM = us;
        const int blk = blockIdx.x - 64;
        const int M0 = (blk >> 3) * 128, N0 = (blk & 7) * 128;
        const int K = 1024;
        const int lane = tid & 63;
        const int w = tid >> 6, wr = w >> 1, wc = w & 1;
        const int r15 = lane & 15, kg = lane >> 4;
        const int lr = lane >> 2, lc = (lane & 3) * 8;

        const unsigned short* Arow0 = NORM + (size_t)(M0 + w * 16 + lr) * K + lc;
        const unsigned short* Arow1 = NORM + (size_t)(M0 + 64 + w * 16 + lr) * K + lc;
        const unsigned short* Brow0 = WQT + (size_t)(N0 + w * 16 + lr) * K + lc;
        const unsigned short* Brow1 = WQT + (size_t)(N0 + 64 + w * 16 + lr) * K + lc;

        f32x4 acc[4][4] = {};

        ASYNC16(Arow0, &SMEM[(w * 16) * 32]);
        ASYNC16(Arow1, &SMEM[(64 + w * 16) * 32]);
        ASYNC16(Brow0, &SMEM[8192 + (w * 16) * 32]);
        ASYNC16(Brow1, &SMEM[8192 + (64 + w * 16) * 32]);

        int cur = 0;
        for (int k0 = 0; k0 < K; k0 += 32) {
            if (k0 + 32 < K) {
                const int nb = (cur ^ 1) * 4096;
                ASYNC16(Arow0 + k0 + 32, &SMEM[nb + (w * 16) * 32]);
                ASYNC16(Arow1 + k0 + 32, &SMEM[nb + (64 + w * 16) * 32]);
                ASYNC16(Brow0 + k0 + 32, &SMEM[8192 + nb + (w * 16) * 32]);
                ASYNC16(Brow1 + k0 + 32, &SMEM[8192 + nb + (64 + w * 16) * 32]);
                __asm__ volatile("s_waitcnt vmcnt(4)" ::: "memory");
            } else {
                __asm__ volatile("s_waitcnt vmcnt(0)" ::: "memory");
            }
            __builtin_amdgcn_s_barrier();
            __builtin_amdgcn_sched_barrier(0);
            const int cb = cur * 4096;
            short8 af[4], bf[4];
#pragma unroll
            for (int m = 0; m < 4; m++)
                af[m] = *(const short8*)&SMEM[cb + (wr * 64 + m * 16 + r15) * 32 + kg * 8];
#pragma unroll
            for (int n = 0; n < 4; n++)
                bf[n] = *(const short8*)&SMEM[8192 + cb + (wc * 64 + n * 16 + r15) * 32 + kg * 8];
#pragma unroll
            for (int m = 0; m < 4; m++)
#pragma unroll
                for (int n = 0; n < 4; n++)
                    acc[m][n] = __builtin_amdgcn_mfma_f32_16x16x32_bf16(af[m], bf[n], acc[m][n], 0, 0, 0);
            __builtin_amdgcn_sched_barrier(0);
            __builtin_amdgcn_s_barrier();
            cur ^= 1;
        }

        float bias_r[4];
#pragma unroll
        for (int n = 0; n < 4; n++) bias_r[n] = bias[N0 + wc * 64 + n * 16 + r15];
        const int hA = N0 >> 6;
#pragma unroll
        for (int p = 0; p < 2; ++p) {
            __syncthreads();
            if (wr == p) {
#pragma unroll
                for (int m = 0; m < 4; m++)
#pragma unroll
                    for (int n = 0; n < 4; n++)
#pragma unroll
                        for (int j = 0; j < 4; j++)
                            SMEM[(m * 16 + kg * 4 + j) * 136 + wc * 64 + n * 16 + r15] =
                                f2bf(acc[m][n][j] + bias_r[n]);
            }
            __syncthreads();
            const int tl = tid >> 2, sg = tid & 3;
            const int gm = M0 + p * 64 + tl;
            const int b = gm >> 11, t = gm & 2047;
            const int h = hA + (sg >> 1), d0 = (sg & 1) * 32;
            const int colbase = sg * 32;
            const size_t dst = ((size_t)(b * 16 + h) * 2048 + t) * 64 + d0;
#pragma unroll
            for (int i = 0; i < 4; i++) {
                uint4 v = *(const uint4*)&SMEM[tl * 136 + colbase + i * 8];
                *(uint4*)(qo + dst + i * 8) = v;
            }
        }
    } else {
        // ======== w_out transpose: f32 [1024][1024] -> bf16 ^T ========
        float* tile = (float*)POOL;   // [32][33]
        const int blk = blockIdx.x - 64 - 512;
        const int c0 = (blk & 31) * 32, r0 = (blk >> 5) * 32;
        const int tx = tid & 31, ty = tid >> 5;
#pragma unroll
        for (int yy = 0; yy < 32; yy += 8)
            tile[(ty + yy) * 33 + tx] = w_out[(size_t)(r0 + ty + yy) * 1024 + c0 + tx];
        __syncthreads();
#pragma unroll
        for (int yy = 0; yy < 32; yy += 8)
            WOT[(size_t)(c0 + ty + yy) * 1024 + r0 + tx] = f2bf(tile[tx * 33 + ty + yy]);
    }
}

// ---------- O kernel: O = Q S_c^T + tril(Q K^T) U'  -> ATTN bf16 ----------
__global__ __launch_bounds__(256) void out_kernel(
    const unsigned short* __restrict__ Qb, const unsigned short* __restrict__ Kb,
    const unsigned short* __restrict__ Scg, const unsigned short* __restrict__ UTg,
    unsigned short* __restrict__ attn)
{
    __shared__ __align__(16) unsigned short Qs[64 * P72];
    __shared__ __align__(16) unsigned short Kbs[64 * P72];
    __shared__ __align__(16) unsigned short Scs[64 * P72];
    __shared__ __align__(16) unsigned short UTss[64 * P72];
    __shared__ __align__(16) unsigned short Ms[64 * P72];
    __shared__ __align__(16) unsigned short Osb[64 * P72];
    const int blk = blockIdx.x, tid = threadIdx.x;
    const int bh = blk >> 5, cc = blk & 31;
    const size_t gbase = (size_t)blk * 4096;
    const int lane = tid & 63, w = tid >> 6;
    const int r15 = lane & 15, kg = lane >> 4;
    {
        const int r0 = tid >> 2, c0 = (tid & 3) * 16;
        uint4 q0 = *(const uint4*)(Qb + gbase + r0 * 64 + c0),  q1 = *(const uint4*)(Qb + gbase + r0 * 64 + c0 + 8);
        uint4 k0 = *(const uint4*)(Kb + gbase + r0 * 64 + c0),  k1 = *(const uint4*)(Kb + gbase + r0 * 64 + c0 + 8);
        uint4 s0 = *(const uint4*)(Scg + gbase + r0 * 64 + c0), s1 = *(const uint4*)(Scg + gbase + r0 * 64 + c0 + 8);
        uint4 u0 = *(const uint4*)(UTg + gbase + r0 * 64 + c0), u1 = *(const uint4*)(UTg + gbase + r0 * 64 + c0 + 8);
        *(uint4*)&Qs [r0 * P72 + c0] = q0; *(uint4*)&Qs [r0 * P72 + c0 + 8] = q1;
        *(uint4*)&Kbs[r0 * P72 + c0] = k0; *(uint4*)&Kbs[r0 * P72 + c0 + 8] = k1;
        *(uint4*)&Scs[r0 * P72 + c0] = s0; *(uint4*)&Scs[r0 * P72 + c0 + 8] = s1;
        *(uint4*)&UTss[r0 * P72 + c0] = u0; *(uint4*)&UTss[r0 * P72 + c0 + 8] = u1;
    }
    __syncthreads();
    {
        f32x4 accm[4] = {{0,0,0,0},{0,0,0,0},{0,0,0,0},{0,0,0,0}};
#pragma unroll
        for (int ks = 0; ks < 2; ks++) {
            short8 afr = *(const short8*)&Qs[(w * 16 + r15) * P72 + ks * 32 + kg * 8];
#pragma unroll
            for (int n = 0; n < 4; n++) {
                short8 bfr = *(const short8*)&Kbs[(n * 16 + r15) * P72 + ks * 32 + kg * 8];
                accm[n] = __builtin_amdgcn_mfma_f32_16x16x32_bf16(afr, bfr, accm[n], 0, 0, 0);
            }
        }
#pragma unroll
        for (int n = 0; n < 4; n++)
#pragma unroll
            for (int j = 0; j < 4; j++) {
                const int t = w * 16 + kg * 4 + j, s = n * 16 + r15;
                Ms[t * P72 + s] = (s <= t) ? f2bf(accm[n][j]) : (unsigned short)0;
            }
    }
    __syncthreads();
    {
        f32x4 acc[4] = {{0,0,0,0},{0,0,0,0},{0,0,0,0},{0,0,0,0}};
#pragma unroll
        for (int ks = 0; ks < 2; ks++) {
            short8 afr = *(const short8*)&Qs[(w * 16 + r15) * P72 + ks * 32 + kg * 8];
#pragma unroll
            for (int n = 0; n < 4; n++) {
                short8 bfr = *(const short8*)&Scs[(n * 16 + r15) * P72 + ks * 32 + kg * 8];
                acc[n] = __builtin_amdgcn_mfma_f32_16x16x32_bf16(afr, bfr, acc[n], 0, 0, 0);
            }
        }
#pragma unroll
        for (int ks = 0; ks < 2; ks++) {
            short8 afr = *(const short8*)&Ms[(w * 16 + r15) * P72 + ks * 32 + kg * 8];
#pragma unroll
            for (int n = 0; n < 4; n++) {
                short8 bfr = *(const short8*)&UTss[(n * 16 + r15) * P72 + ks * 32 + kg * 8];
                acc[n] = __builtin_amdgcn_mfma_f32_16x16x32_bf16(afr, bfr, acc[n], 0, 0, 0);
            }
        }
#pragma unroll
        for (int n = 0; n < 4; n++)
#pragma unroll
            for (int j = 0; j < 4; j++) {
                const int t = w * 16 + kg * 4 + j, i = n * 16 + r15;
                Osb[t * P72 + i] = f2bf(acc[n][j]);
            }
    }
    __syncthreads();
    {
        const int b = bh >> 4, h = bh & 15;
        const int t = tid >> 2, i0 = (tid & 3) * 16;
        uint4 o0 = *(const uint4*)&Osb[t * P72 + i0];
        uint4 o1 = *(const uint4*)&Osb[t * P72 + i0 + 8];
        unsigned short* dst = attn + ((size_t)(b * 2048 + cc * 64 + t)) * 1024 + h * 64 + i0;
        *(uint4*)dst = o0;
        *(uint4*)(dst + 8) = o1;
    }
}

// ---------- launch ----------
extern "C" void kernel_launch(void* const* d_in, const int* in_sizes, int n_in,
                              void* d_out, int out_size, void* d_ws, size_t ws_size,
                              hipStream_t stream)
{
    const float* x      = (const float*)d_in[0];
    const float* ln_g   = (const float*)d_in[1];
    const float* ln_b   = (const float*)d_in[2];
    const float* w_qkvb = (const float*)d_in[3];
    const float* b_qkvb = (const float*)d_in[4];
    const float* w_out  = (const float*)d_in[5];
    const float* b_out  = (const float*)d_in[6];
    float* out = (float*)d_out;

    char* ws = (char*)d_ws;
    size_t off = 0;
    auto alloc = [&](size_t bytes) -> char* {
        char* p = ws + off;
        off = (off + bytes + 255) & ~(size_t)255;
        return p;
    };
    const size_t TOK = 64ull * 2048 * 64;
    unsigned short* WQT  = (unsigned short*)alloc(4096ull * 1024 * 2);
    unsigned short* WOT  = (unsigned short*)alloc(1024ull * 1024 * 2);
    unsigned short* NORM = (unsigned short*)alloc(TOK * 2 * 2);
    unsigned short* Qb   = (unsigned short*)alloc(TOK * 2);
    unsigned short* Kpre = (unsigned short*)alloc(TOK * 2);
    unsigned short* Kb   = (unsigned short*)alloc(TOK * 2);
    unsigned short* KTb  = (unsigned short*)alloc(TOK * 2);
    unsigned short* Vb   = (unsigned short*)alloc(TOK * 2);
    unsigned short* Bb   = (unsigned short*)alloc(TOK * 2);
    unsigned short* A0   = (unsigned short*)alloc(TOK * 2);
    unsigned short* Sc   = (unsigned short*)alloc(TOK * 2);
    unsigned short* UT   = (unsigned short*)alloc(TOK * 2);
    float*          A0D  = (float*)alloc(2048ull * 1024 * 4);
    unsigned short* ATTN = NORM;   // NORM dead after fused (Q-GEMM reads it there)
    unsigned short* VTb  = Vb;     // prep transposes in place (per-block disjoint r/w)
    unsigned short* BTb  = Bb;

    hipLaunchKernelGGL(ln_wqt_kernel, dim3(8192 + 4096), dim3(256), 0, stream,
                       x, ln_g, ln_b, NORM, w_qkvb, WQT);
    // gemm1a: K,V,beta only (cols 1024..4095) — 256x128 phase-interleaved kernel
    hipLaunchKernelGGL(gemm256, dim3(24, 32), dim3(512), 0, stream,
                       NORM, WQT, b_qkvb, 1024, 1024, Qb, Kpre, Vb, Bb);
    hipLaunchKernelGGL(prep_kernel, dim3(2048), dim3(256), 0, stream,
                       Kpre, Vb, Bb, Kb, A0, A0D, KTb, VTb, BTb);
    // fused: scan (64) | Q-GEMM (512) | w_out transpose (1024)
    hipLaunchKernelGGL(fused_scan_kernel, dim3(64 + 512 + 1024), dim3(256), 0, stream,
                       A0, Kb, KTb, A0D, VTb, BTb, Sc, UT,
                       NORM, WQT, b_qkvb, Qb, w_out, WOT);
    hipLaunchKernelGGL(out_kernel, dim3(2048), dim3(256), 0, stream, Qb, Kb, Sc, UT, ATTN);
    hipLaunchKernelGGL(gemm128, dim3(8, 64), dim3(256), 0, stream,
                       ATTN, WOT, b_out, 1024, 1024, 1, 0,
                       x, out, (unsigned short*)nullptr, (unsigned short*)nullptr,
                       (unsigned short*)nullptr, (unsigned short*)nullptr);
}

// Round 2
// 317.652 us; speedup vs baseline: 1.0398x; 1.0398x over previous
//
#include <hip/hip_runtime.h>
#include <hip/hip_bf16.h>

// ---------- types ----------
typedef __attribute__((ext_vector_type(8))) short short8;   // 8 x bf16 bits
typedef __attribute__((ext_vector_type(4))) float f32x4;

#define P72 72    // bf16 tile pitch (ushorts): 144B rows, 16B-aligned

__device__ __forceinline__ unsigned short f2bf(float f) {
    union { float f; unsigned int u; } v; v.f = f;
    unsigned int r = (v.u + 0x7FFFu + ((v.u >> 16) & 1u)) >> 16;
    return (unsigned short)r;
}
__device__ __forceinline__ float bf2f(unsigned short b) {
    union { unsigned int u; float f; } v; v.u = ((unsigned int)b) << 16; return v.f;
}

#define WAVE_SYNC() do { __asm__ volatile("s_waitcnt lgkmcnt(0)" ::: "memory"); \
                         __builtin_amdgcn_sched_barrier(0); } while (0)

// block barrier WITHOUT vmcnt drain: LDS visibility only (stores keep draining
// in background — keeps fire-and-forget global stores off the serial chain)
#define LGKM_BARRIER() do { __asm__ volatile("s_waitcnt lgkmcnt(0)" ::: "memory"); \
                            __builtin_amdgcn_s_barrier(); \
                            __builtin_amdgcn_sched_barrier(0); } while (0)

#define ASYNC16(G, L) __builtin_amdgcn_global_load_lds( \
    (const __attribute__((address_space(1))) void*)(G), \
    (__attribute__((address_space(3))) void*)(L), 16, 0, 0)

// ---------- fused LayerNorm (blocks 0..8191) + w_qkvb transpose (8192..12287) ----------
__global__ __launch_bounds__(256) void ln_wqt_kernel(
    const float* __restrict__ x, const float* __restrict__ g,
    const float* __restrict__ bv_, unsigned short* __restrict__ out,
    const float* __restrict__ w_qkvb, unsigned short* __restrict__ WQT)
{
    __shared__ float pool[32 * 33];
    const int tid = threadIdx.x;
    if (blockIdx.x < 8192) {
        const int row = blockIdx.x;
        const float4 v = ((const float4*)(x + (size_t)row * 1024))[tid];
        float s  = v.x + v.y + v.z + v.w;
        float s2 = v.x * v.x + v.y * v.y + v.z * v.z + v.w * v.w;
#pragma unroll
        for (int off = 1; off < 64; off <<= 1) {
            s  += __shfl_xor(s, off);
            s2 += __shfl_xor(s2, off);
        }
        const int wv = tid >> 6;
        if ((tid & 63) == 0) { pool[wv] = s; pool[4 + wv] = s2; }
        __syncthreads();
        s  = pool[0] + pool[1] + pool[2] + pool[3];
        s2 = pool[4] + pool[5] + pool[6] + pool[7];
        const float mu  = s * (1.0f / 1024.0f);
        const float var = s2 * (1.0f / 1024.0f) - mu * mu;
        const float inv = rsqrtf(var + 1e-5f);
        const float4 gv = ((const float4*)g)[tid];
        const float4 bb = ((const float4*)bv_)[tid];
        ushort4 o;
        o.x = f2bf((v.x - mu) * inv * gv.x + bb.x);
        o.y = f2bf((v.y - mu) * inv * gv.y + bb.y);
        o.z = f2bf((v.z - mu) * inv * gv.z + bb.z);
        o.w = f2bf((v.w - mu) * inv * gv.w + bb.w);
        *(ushort4*)(out + (size_t)row * 1024 + tid * 4) = o;
    } else {
        // transpose f32 w_qkvb[1024][4096] -> bf16 WQT[4096][1024]
        const int blk = blockIdx.x - 8192;
        const int c0 = (blk & 127) * 32, r0 = (blk >> 7) * 32;
        const int tx = tid & 31, ty = tid >> 5;   // 32 x 8
#pragma unroll
        for (int yy = 0; yy < 32; yy += 8)
            pool[(ty + yy) * 33 + tx] = w_qkvb[(size_t)(r0 + ty + yy) * 4096 + c0 + tx];
        __syncthreads();
#pragma unroll
        for (int yy = 0; yy < 32; yy += 8)
            WQT[(size_t)(c0 + ty + yy) * 1024 + r0 + tx] = f2bf(pool[tx * 33 + ty + yy]);
    }
}

// ---------- 128x128 MFMA GEMM — 3-buffer, counted vmcnt(8), XCD-swizzled ----------
// (used for the output projection, mode 1)
__global__ __launch_bounds__(256) void gemm128(
    const unsigned short* __restrict__ A, const unsigned short* __restrict__ Bt,
    const float* __restrict__ bias, int K, int N, int mode, int n0_off,
    const float* __restrict__ resid, float* __restrict__ outf,
    unsigned short* __restrict__ qo, unsigned short* __restrict__ ko,
    unsigned short* __restrict__ vo, unsigned short* __restrict__ bo)
{
    __shared__ __align__(16) unsigned short SMEM[24576];  // 48KB
    const int tid = threadIdx.x;
    // T1: bijective XCD swizzle — each XCD gets a contiguous tile range
    const int nwg = (int)(gridDim.x * gridDim.y);
    const int flat = (int)(blockIdx.y * gridDim.x + blockIdx.x);
    const int id2 = (flat & 7) * (nwg >> 3) + (flat >> 3);
    const int M0 = (id2 / (int)gridDim.x) * 128;
    const int N0 = (id2 % (int)gridDim.x) * 128 + n0_off;
    const int lane = tid & 63;
    const int w = tid >> 6, wr = w >> 1, wc = w & 1;
    const int r15 = lane & 15, kg = lane >> 4;
    const int lr = lane >> 2, lc = (lane & 3) * 8;

    const unsigned short* Arow0 = A  + (size_t)(M0 + w * 16 + lr) * K + lc;
    const unsigned short* Arow1 = A  + (size_t)(M0 + 64 + w * 16 + lr) * K + lc;
    const unsigned short* Brow0 = Bt + (size_t)(N0 + w * 16 + lr) * K + lc;
    const unsigned short* Brow1 = Bt + (size_t)(N0 + 64 + w * 16 + lr) * K + lc;

    f32x4 acc[4][4] = {};

    ASYNC16(Arow0, &SMEM[(w * 16) * 32]);
    ASYNC16(Arow1, &SMEM[(64 + w * 16) * 32]);
    ASYNC16(Brow0, &SMEM[12288 + (w * 16) * 32]);
    ASYNC16(Brow1, &SMEM[12288 + (64 + w * 16) * 32]);
    if (32 < K) {
        ASYNC16(Arow0 + 32, &SMEM[4096 + (w * 16) * 32]);
        ASYNC16(Arow1 + 32, &SMEM[4096 + (64 + w * 16) * 32]);
        ASYNC16(Brow0 + 32, &SMEM[12288 + 4096 + (w * 16) * 32]);
        ASYNC16(Brow1 + 32, &SMEM[12288 + 4096 + (64 + w * 16) * 32]);
    }

    int cur = 0;
    for (int k0 = 0; k0 < K; k0 += 32) {
        if (k0 + 64 < K) {
            int n2 = cur + 2; if (n2 >= 3) n2 -= 3;
            const int nb = n2 * 4096;
            ASYNC16(Arow0 + k0 + 64, &SMEM[nb + (w * 16) * 32]);
            ASYNC16(Arow1 + k0 + 64, &SMEM[nb + (64 + w * 16) * 32]);
            ASYNC16(Brow0 + k0 + 64, &SMEM[12288 + nb + (w * 16) * 32]);
            ASYNC16(Brow1 + k0 + 64, &SMEM[12288 + nb + (64 + w * 16) * 32]);
            __asm__ volatile("s_waitcnt vmcnt(8)" ::: "memory");
        } else if (k0 + 32 < K) {
            __asm__ volatile("s_waitcnt vmcnt(4)" ::: "memory");
        } else {
            __asm__ volatile("s_waitcnt vmcnt(0)" ::: "memory");
        }
        __builtin_amdgcn_s_barrier();
        __builtin_amdgcn_sched_barrier(0);
        const int cb = cur * 4096;
        short8 af[4], bf[4];
#pragma unroll
        for (int m = 0; m < 4; m++)
            af[m] = *(const short8*)&SMEM[cb + (wr * 64 + m * 16 + r15) * 32 + kg * 8];
#pragma unroll
        for (int n = 0; n < 4; n++)
            bf[n] = *(const short8*)&SMEM[12288 + cb + (wc * 64 + n * 16 + r15) * 32 + kg * 8];
#pragma unroll
        for (int m = 0; m < 4; m++)
#pragma unroll
            for (int n = 0; n < 4; n++)
                acc[m][n] = __builtin_amdgcn_mfma_f32_16x16x32_bf16(af[m], bf[n], acc[m][n], 0, 0, 0);
        __builtin_amdgcn_sched_barrier(0);
        __builtin_amdgcn_s_barrier();
        cur += 1; if (cur >= 3) cur = 0;
    }

    float bias_r[4];
#pragma unroll
    for (int n = 0; n < 4; n++) bias_r[n] = bias[N0 + wc * 64 + n * 16 + r15];

    if (mode == 0) {
        const int sec = N0 >> 10;
        const int hA = (N0 & 1023) >> 6;
        unsigned short* arr = (sec == 0) ? qo : (sec == 1) ? ko : (sec == 2) ? vo : bo;
#pragma unroll
        for (int p = 0; p < 2; ++p) {
            __syncthreads();
            if (wr == p) {
#pragma unroll
                for (int m = 0; m < 4; m++)
#pragma unroll
                    for (int n = 0; n < 4; n++)
#pragma unroll
                        for (int j = 0; j < 4; j++) {
                            float val = acc[m][n][j] + bias_r[n];
                            if (sec == 3) val = 1.0f / (1.0f + expf(-val));
                            SMEM[(m * 16 + kg * 4 + j) * 136 + wc * 64 + n * 16 + r15] = f2bf(val);
                        }
            }
            __syncthreads();
            const int tl = tid >> 2, sg = tid & 3;
            const int gm = M0 + p * 64 + tl;
            const int b = gm >> 11, t = gm & 2047;
            const int h = hA + (sg >> 1), d0 = (sg & 1) * 32;
            const int colbase = sg * 32;
            const size_t dst = ((size_t)(b * 16 + h) * 2048 + t) * 64 + d0;
#pragma unroll
            for (int i = 0; i < 4; i++) {
                uint4 v = *(const uint4*)&SMEM[tl * 136 + colbase + i * 8];
                *(uint4*)(arr + dst + i * 8) = v;
            }
        }
    } else {
        float* stf = (float*)SMEM;
#pragma unroll
        for (int p = 0; p < 4; ++p) {
            __syncthreads();
            if (wr == (p >> 1)) {
#pragma unroll
                for (int mm = 0; mm < 2; mm++)
#pragma unroll
                    for (int n = 0; n < 4; n++)
#pragma unroll
                        for (int j = 0; j < 4; j++)
                            stf[(mm * 16 + kg * 4 + j) * 132 + wc * 64 + n * 16 + r15] =
                                acc[(p & 1) * 2 + mm][n][j] + bias_r[n];
            }
            __syncthreads();
            const int rl = tid >> 3, sg = (tid & 7) * 16;
            const size_t rowo = (size_t)(M0 + p * 32 + rl) * N + N0 + sg;
#pragma unroll
            for (int i = 0; i < 4; i++) {
                float4 v = *(const float4*)&stf[rl * 132 + sg + i * 4];
                float4 r = *(const float4*)(resid + rowo + i * 4);
                v.x += r.x; v.y += r.y; v.z += r.z; v.w += r.w;
                *(float4*)(outf + rowo + i * 4) = v;
            }
        }
    }
}

// ---------- 256x128 phase-interleaved MFMA GEMM (T2+T3+T4+T5) for the QKVB proj ----
// 512 threads = 8 waves (2M x 4N), BK=64, 3 LDS buffers (144KB), counted vmcnt(6).
// L2-GROUPED XCD swizzle (hardcoded for grid 24x32, nwg=768, 96 blocks/XCD):
//   each XCD works in groups of 2 M-panels x 8 N-tiles (working set 3MB <= 4MB L2);
//   A-panels reused across 3 consecutive N-groups, B chunks refetched only 2x from L3.
__global__ __launch_bounds__(512, 2) void gemm256(
    const unsigned short* __restrict__ A, const unsigned short* __restrict__ Bt,
    const float* __restrict__ bias, int K, int n0_off,
    unsigned short* __restrict__ qo, unsigned short* __restrict__ ko,
    unsigned short* __restrict__ vo, unsigned short* __restrict__ bo)
{
    __shared__ __align__(16) unsigned short SMEM[73728];   // 144KB: 3 x (A 32KB + B 16KB)
    const int tid = threadIdx.x;
    const int flat = (int)(blockIdx.y * gridDim.x + blockIdx.x);
    // L2-grouped mapping: xcd = flat&7 (HW round-robin), l in [0,96)
    const int xcd = flat & 7;
    const int l   = flat >> 3;
    const int grp = l >> 4;            // 6 groups: 2 (M) x 3 (N)
    const int gi  = l & 15;            // 16 blocks/group: 2 (M) x 8 (N)
    const int gM  = grp / 3, gN = grp % 3;
    const int mp  = xcd * 4 + gM * 2 + (gi >> 3);   // M-panel 0..31
    const int nt  = gN * 8 + (gi & 7);              // N-tile 0..23
    const int M0 = mp * 256;
    const int N0 = nt * 128 + n0_off;

    const int lane = tid & 63, wv = tid >> 6;
    const int wr = wv >> 2, wc = wv & 3;           // wave grid 2 (M) x 4 (N)
    const int r15 = lane & 15, kg = lane >> 4;
    const int swz = r15 & 7;                       // read-side XOR (row&7 == r15&7)

    // staging source: lane covers (row = 8i + l>>3, stored chunk = l&7) which must
    // hold global chunk (l&7) ^ (l>>3)   [8 chunks of 16B per 128B row]
    const int srow = lane >> 3;
    const int schk = (lane & 7) ^ srow;
    const unsigned short* Asrc = A  + (size_t)(M0 + wv * 8 + srow) * K + schk * 8;
    const unsigned short* Bsrc = Bt + (size_t)(N0 + wv * 8 + srow) * K + schk * 8;

    // bias first: its 2 vmem ops are oldest, drain before any counted wait matters
    float bias_r[2];
    bias_r[0] = bias[N0 + wc * 32 + r15];
    bias_r[1] = bias[N0 + wc * 32 + 16 + r15];
    __builtin_amdgcn_sched_barrier(0);

    auto stageA = [&](int b_, int ko_, int i_) {
        ASYNC16(Asrc + (size_t)i_ * 64 * K + ko_,
                &SMEM[b_ * 24576 + (i_ * 64 + wv * 8) * 64]);
    };
    auto stageB = [&](int b_, int ko_, int i_) {
        ASYNC16(Bsrc + (size_t)i_ * 64 * K + ko_,
                &SMEM[b_ * 24576 + 16384 + (i_ * 64 + wv * 8) * 64]);
    };

    // prologue: stage K-tiles 0 and 1 (6 ops each: A i=0..3, B i=0..1)
#pragma unroll
    for (int i = 0; i < 4; i++) stageA(0, 0, i);
    stageB(0, 0, 0); stageB(0, 0, 1);
#pragma unroll
    for (int i = 0; i < 4; i++) stageA(1, 64, i);
    stageB(1, 64, 0); stageB(1, 64, 1);

    f32x4 acc[8][2] = {};

#define PH_PRE() do { __builtin_amdgcn_s_barrier(); \
                      __asm__ volatile("s_waitcnt lgkmcnt(0)" ::: "memory"); \
                      __builtin_amdgcn_sched_barrier(0); \
                      __builtin_amdgcn_s_setprio(1); } while (0)
#define PH_POST() do { __builtin_amdgcn_s_setprio(0); \
                       __builtin_amdgcn_sched_barrier(0); \
                       __builtin_amdgcn_s_barrier(); } while (0)

    const int NT = K >> 6;
    int cur = 0;
    for (int t = 0; t < NT; ++t) {
        // tile-top: drain this tile's 6 stage ops, leave the next tile's in flight
        if (t + 1 < NT) { __asm__ volatile("s_waitcnt vmcnt(6)" ::: "memory"); }
        else            { __asm__ volatile("s_waitcnt vmcnt(0)" ::: "memory"); }
        __builtin_amdgcn_s_barrier();
        __builtin_amdgcn_sched_barrier(0);

        const unsigned short* Ab = &SMEM[cur * 24576];
        const unsigned short* Bb = &SMEM[cur * 24576 + 16384];
        int nb = cur + 2; if (nb >= 3) nb -= 3;
        const int nko = (t + 2) * 64;
        const bool pf = (t + 2 < NT);

        short8 af[4], bf[2];
        // ---- phase 0: ks=0, m=0..3 (B n=0..1 read here, reused in phase 1) ----
#pragma unroll
        for (int m = 0; m < 4; m++)
            af[m] = *(const short8*)&Ab[(wr * 128 + m * 16 + r15) * 64 + (kg ^ swz) * 8];
#pragma unroll
        for (int n = 0; n < 2; n++)
            bf[n] = *(const short8*)&Bb[(wc * 32 + n * 16 + r15) * 64 + (kg ^ swz) * 8];
        if (pf) { stageA(nb, nko, 0); stageA(nb, nko, 1); }
        PH_PRE();
#pragma unroll
        for (int m = 0; m < 4; m++)
#pragma unroll
            for (int n = 0; n < 2; n++)
                acc[m][n] = __builtin_amdgcn_mfma_f32_16x16x32_bf16(af[m], bf[n], acc[m][n], 0, 0, 0);
        PH_POST();
        // ---- phase 1: ks=0, m=4..7 ----
#pragma unroll
        for (int m = 0; m < 4; m++)
            af[m] = *(const short8*)&Ab[(wr * 128 + (m + 4) * 16 + r15) * 64 + (kg ^ swz) * 8];
        if (pf) { stageA(nb, nko, 2); stageA(nb, nko, 3); }
        PH_PRE();
#pragma unroll
        for (int m = 0; m < 4; m++)
#pragma unroll
            for (int n = 0; n < 2; n++)
                acc[m + 4][n] = __builtin_amdgcn_mfma_f32_16x16x32_bf16(af[m], bf[n], acc[m + 4][n], 0, 0, 0);
        PH_POST();
        // ---- phase 2: ks=1, m=0..3 ----
#pragma unroll
        for (int m = 0; m < 4; m++)
            af[m] = *(const short8*)&Ab[(wr * 128 + m * 16 + r15) * 64 + ((4 + kg) ^ swz) * 8];
#pragma unroll
        for (int n = 0; n < 2; n++)
            bf[n] = *(const short8*)&Bb[(wc * 32 + n * 16 + r15) * 64 + ((4 + kg) ^ swz) * 8];
        if (pf) { stageB(nb, nko, 0); stageB(nb, nko, 1); }
        PH_PRE();
#pragma unroll
        for (int m = 0; m < 4; m++)
#pragma unroll
            for (int n = 0; n < 2; n++)
                acc[m][n] = __builtin_amdgcn_mfma_f32_16x16x32_bf16(af[m], bf[n], acc[m][n], 0, 0, 0);
        PH_POST();
        // ---- phase 3: ks=1, m=4..7 (no trailing barrier: tile-top covers it) ----
#pragma unroll
        for (int m = 0; m < 4; m++)
            af[m] = *(const short8*)&Ab[(wr * 128 + (m + 4) * 16 + r15) * 64 + ((4 + kg) ^ swz) * 8];
        PH_PRE();
#pragma unroll
        for (int m = 0; m < 4; m++)
#pragma unroll
            for (int n = 0; n < 2; n++)
                acc[m + 4][n] = __builtin_amdgcn_mfma_f32_16x16x32_bf16(af[m], bf[n], acc[m + 4][n], 0, 0, 0);
        __builtin_amdgcn_s_setprio(0);
        __builtin_amdgcn_sched_barrier(0);

        cur += 1; if (cur >= 3) cur = 0;
    }
#undef PH_PRE
#undef PH_POST

    // ---- epilogue: stage bf16 via LDS, scatter to per-head [b,h,t,d] layout ----
    const int sec = N0 >> 10;
    const int hA = (N0 & 1023) >> 6;
    unsigned short* arr = (sec == 0) ? qo : (sec == 1) ? ko : (sec == 2) ? vo : bo;
#pragma unroll
    for (int p = 0; p < 2; ++p) {
        __syncthreads();
        if (wr == p) {
#pragma unroll
            for (int m = 0; m < 8; m++)
#pragma unroll
                for (int n = 0; n < 2; n++)
#pragma unroll
                    for (int j = 0; j < 4; j++) {
                        float val = acc[m][n][j] + bias_r[n];
                        if (sec == 3) val = 1.0f / (1.0f + expf(-val));
                        SMEM[(m * 16 + kg * 4 + j) * 136 + wc * 32 + n * 16 + r15] = f2bf(val);
                    }
        }
        __syncthreads();
        const int row = tid >> 2, sg = tid & 3;
        const int gm = M0 + p * 128 + row;
        const int b = gm >> 11, tt = gm & 2047;
        const int h = hA + (sg >> 1), d0 = (sg & 1) * 32;
        const size_t dst = ((size_t)(b * 16 + h) * 2048 + tt) * 64 + d0;
#pragma unroll
        for (int i = 0; i < 4; i++) {
            uint4 v = *(const uint4*)&SMEM[row * 136 + sg * 32 + i * 8];
            *(uint4*)(arr + dst + i * 8) = v;
        }
    }
}

// ---------- prep: normalize K; A0=tril_strict(KK^T) bf16; A0D f32 diag blocks;
//            KT, VT, BT transposes.  grid 2048 = bh*32 + c ----------
__global__ __launch_bounds__(256) void prep_kernel(
    const unsigned short* __restrict__ Kpre, const unsigned short* __restrict__ Vin,
    const unsigned short* __restrict__ Bin,
    unsigned short* __restrict__ Kb, unsigned short* __restrict__ A0g,
    float* __restrict__ A0Dg, unsigned short* __restrict__ KTg,
    unsigned short* __restrict__ VTg, unsigned short* __restrict__ BTg)
{
    __shared__ __align__(16) unsigned short Ks[64 * P72];
    __shared__ __align__(16) unsigned short Vs[64 * P72];
    __shared__ __align__(16) unsigned short Bs[64 * P72];
    __shared__ __align__(16) unsigned short Os[64 * P72];
    const int cid = blockIdx.x, tid = threadIdx.x;
    const size_t gbase = (size_t)cid * 4096;
    const int r0 = tid >> 2, c0 = (tid & 3) * 16;
    {
        uint4 k0 = *(const uint4*)(Kpre + gbase + r0 * 64 + c0), k1 = *(const uint4*)(Kpre + gbase + r0 * 64 + c0 + 8);
        uint4 v0 = *(const uint4*)(Vin + gbase + r0 * 64 + c0),  v1 = *(const uint4*)(Vin + gbase + r0 * 64 + c0 + 8);
        uint4 b0 = *(const uint4*)(Bin + gbase + r0 * 64 + c0),  b1 = *(const uint4*)(Bin + gbase + r0 * 64 + c0 + 8);
        *(uint4*)&Ks[r0 * P72 + c0] = k0; *(uint4*)&Ks[r0 * P72 + c0 + 8] = k1;
        *(uint4*)&Vs[r0 * P72 + c0] = v0; *(uint4*)&Vs[r0 * P72 + c0 + 8] = v1;
        *(uint4*)&Bs[r0 * P72 + c0] = b0; *(uint4*)&Bs[r0 * P72 + c0 + 8] = b1;
    }
    __syncthreads();
    {
        const int row = tid >> 2, seg = tid & 3;
        float v[16]; float ss = 0.f;
#pragma unroll
        for (int q = 0; q < 16; q++) { v[q] = bf2f(Ks[row * P72 + seg * 16 + q]); ss = fmaf(v[q], v[q], ss); }
        ss += __shfl_xor(ss, 1); ss += __shfl_xor(ss, 2);
        const float inv = 1.0f / fmaxf(sqrtf(ss), 1e-6f);
        unsigned short t16[16];
#pragma unroll
        for (int q = 0; q < 16; q++) t16[q] = f2bf(v[q] * inv);
        *(uint4*)&Ks[row * P72 + seg * 16]     = *(uint4*)&t16[0];
        *(uint4*)&Ks[row * P72 + seg * 16 + 8] = *(uint4*)&t16[8];
        *(uint4*)(Kb + gbase + row * 64 + seg * 16)     = *(uint4*)&t16[0];
        *(uint4*)(Kb + gbase + row * 64 + seg * 16 + 8) = *(uint4*)&t16[8];
    }
    __syncthreads();
    const int lane = tid & 63, w = tid >> 6;
    const int r15 = lane & 15, kg = lane >> 4;
    f32x4 acc[4] = {{0,0,0,0},{0,0,0,0},{0,0,0,0},{0,0,0,0}};
#pragma unroll
    for (int ks = 0; ks < 2; ks++) {
        short8 afr = *(const short8*)&Ks[(w * 16 + r15) * P72 + ks * 32 + kg * 8];
#pragma unroll
        for (int n = 0; n < 4; n++) {
            short8 bfr = *(const short8*)&Ks[(n * 16 + r15) * P72 + ks * 32 + kg * 8];
            acc[n] = __builtin_amdgcn_mfma_f32_16x16x32_bf16(afr, bfr, acc[n], 0, 0, 0);
        }
    }
#pragma unroll
    for (int n = 0; n < 4; n++) {
#pragma unroll
        for (int j = 0; j < 4; j++) {
            const int s = w * 16 + kg * 4 + j, r = n * 16 + r15;
            Os[s * P72 + r] = (r < s) ? f2bf(acc[n][j]) : (unsigned short)0;
        }
        if (n == w) {
            float4 d;
            d.x = (r15 < kg * 4 + 0) ? acc[n][0] : 0.f;
            d.y = (r15 < kg * 4 + 1) ? acc[n][1] : 0.f;
            d.z = (r15 < kg * 4 + 2) ? acc[n][2] : 0.f;
            d.w = (r15 < kg * 4 + 3) ? acc[n][3] : 0.f;
            *(float4*)(A0Dg + (size_t)cid * 1024 + w * 256 + r15 * 16 + kg * 4) = d;
        }
    }
    __syncthreads();
    {
        uint4 x0 = *(const uint4*)&Os[r0 * P72 + c0];
        uint4 x1 = *(const uint4*)&Os[r0 * P72 + c0 + 8];
        *(uint4*)(A0g + gbase + r0 * 64 + c0) = x0;
        *(uint4*)(A0g + gbase + r0 * 64 + c0 + 8) = x1;
    }
    {
        const int d = tid >> 2, s0 = (tid & 3) * 16;
        unsigned short tk[16], tv[16], tb[16];
#pragma unroll
        for (int k = 0; k < 16; k++) {
            tk[k] = Ks[(s0 + k) * P72 + d];
            tv[k] = Vs[(s0 + k) * P72 + d];
            tb[k] = Bs[(s0 + k) * P72 + d];
        }
        *(uint4*)(KTg + gbase + (size_t)d * 64 + s0)     = *(uint4*)&tk[0];
        *(uint4*)(KTg + gbase + (size_t)d * 64 + s0 + 8) = *(uint4*)&tk[8];
        *(uint4*)(VTg + gbase + (size_t)d * 64 + s0)     = *(uint4*)&tv[0];
        *(uint4*)(VTg + gbase + (size_t)d * 64 + s0 + 8) = *(uint4*)&tv[8];
        *(uint4*)(BTg + gbase + (size_t)d * 64 + s0)     = *(uint4*)&tb[0];
        *(uint4*)(BTg + gbase + (size_t)d * 64 + s0 + 8) = *(uint4*)&tb[8];
    }
}

// ---------- fused: blocks 0-63 = serial scan; 64-575 = Q-GEMM; 576-1599 = WOT ----------
__global__ __launch_bounds__(256, 1) void fused_scan_kernel(
    const unsigned short* __restrict__ A0g, const unsigned short* __restrict__ Kb,
    const unsigned short* __restrict__ KTg, const float* __restrict__ A0Dg,
    const unsigned short* __restrict__ VTg, const unsigned short* __restrict__ BTg,
    unsigned short* __restrict__ Scg, unsigned short* __restrict__ UTg,
    const unsigned short* __restrict__ NORM, const unsigned short* __restrict__ WQT,
    const float* __restrict__ bias, unsigned short* __restrict__ qo,
    const float* __restrict__ w_out, unsigned short* __restrict__ WOT)
{
    __shared__ __align__(16) unsigned char POOL[120832];
    unsigned short* us = (unsigned short*)POOL;
    const int tid = threadIdx.x;

    if (blockIdx.x < 64) {
        unsigned short* sK  = us;            // [2][4608]
        unsigned short* sKT = us + 9216;
        unsigned short* sA0 = us + 18432;
        unsigned short* sVT = us + 27648;
        unsigned short* sBT = us + 36864;
        float* sA0D = (float*)(POOL + 92160);  // [2][1280]
        unsigned short* Sbf = us + 51200;      // [4608]
        unsigned short* UTs = us + 55808;      // [4608]

        const int bh = blockIdx.x;
        const int lane = tid & 63, w = tid >> 6;
        const int r15 = lane & 15, kg = lane >> 4;
        const int sr = tid >> 2, sc = (tid & 3) * 16;
        const int qr = 16 * w + (lane >> 2), qc = (lane & 3) * 16;
        const size_t base0 = (size_t)bh * 32 * 4096;
        const size_t baseD = (size_t)bh * 32 * 1024;
        const int dOff = (w * 16 + (sr & 15)) * 20 + (tid & 3) * 4;

        f32x4 Sreg[4] = {};
        uint4 g[10]; float4 gD;

        const uint4 z4 = {0u, 0u, 0u, 0u};
        *(uint4*)&Sbf[sr * P72 + sc] = z4;
        *(uint4*)&Sbf[sr * P72 + sc + 8] = z4;
        {
            const size_t gb = base0 + sr * 64 + sc;
            g[0] = *(const uint4*)(Kb  + gb); g[1] = *(const uint4*)(Kb  + gb + 8);
            g[2] = *(const uint4*)(KTg + gb); g[3] = *(const uint4*)(KTg + gb + 8);
            g[4] = *(const uint4*)(A0g + gb); g[5] = *(const uint4*)(A0g + gb + 8);
            g[6] = *(const uint4*)(VTg + gb); g[7] = *(const uint4*)(VTg + gb + 8);
            g[8] = *(const uint4*)(BTg + gb); g[9] = *(const uint4*)(BTg + gb + 8);
            gD   = *(const float4*)(A0Dg + baseD + tid * 4);
            *(uint4*)&sK [sr * P72 + sc] = g[0]; *(uint4*)&sK [sr * P72 + sc + 8] = g[1];
            *(uint4*)&sKT[sr * P72 + sc] = g[2]; *(uint4*)&sKT[sr * P72 + sc + 8] = g[3];
            *(uint4*)&sA0[sr * P72 + sc] = g[4]; *(uint4*)&sA0[sr * P72 + sc + 8] = g[5];
            *(uint4*)&sVT[sr * P72 + sc] = g[6]; *(uint4*)&sVT[sr * P72 + sc + 8] = g[7];
            *(uint4*)&sBT[sr * P72 + sc] = g[8]; *(uint4*)&sBT[sr * P72 + sc + 8] = g[9];
            *(float4*)&sA0D[dOff] = gD;
        }

#pragma unroll 1
        for (int c = 0; c < 32; ++c) {
            const int cur = c & 1, nxt = cur ^ 1;
            LGKM_BARRIER();   // LDS visibility only; global stores drain in background
            if (c < 31) {
                const size_t gb = base0 + (size_t)(c + 1) * 4096 + sr * 64 + sc;
                g[0] = *(const uint4*)(Kb  + gb); g[1] = *(const uint4*)(Kb  + gb + 8);
                g[2] = *(const uint4*)(KTg + gb); g[3] = *(const uint4*)(KTg + gb + 8);
                g[4] = *(const uint4*)(A0g + gb); g[5] = *(const uint4*)(A0g + gb + 8);
                g[6] = *(const uint4*)(VTg + gb); g[7] = *(const uint4*)(VTg + gb + 8);
                g[8] = *(const uint4*)(BTg + gb); g[9] = *(const uint4*)(BTg + gb + 8);
                gD   = *(const float4*)(A0Dg + baseD + (size_t)(c + 1) * 1024 + tid * 4);
            }
            const unsigned short* KsC  = &sK [cur * 4608];
            const unsigned short* KTsC = &sKT[cur * 4608];
            const unsigned short* A0C  = &sA0[cur * 4608];
            const unsigned short* VTC  = &sVT[cur * 4608];
            const unsigned short* BTC  = &sBT[cur * 4608];
            const float*          A0DC = &sA0D[cur * 1280];

            *(uint4*)&UTs[(16 * w + r15) * P72 + kg * 16] = z4;
            *(uint4*)&UTs[(16 * w + r15) * P72 + kg * 16 + 8] = z4;

            {   // snapshot Scg = +S
                uint4 a = *(const uint4*)&Sbf[qr * P72 + qc];
                uint4 b2 = *(const uint4*)&Sbf[qr * P72 + qc + 8];
                const unsigned FL = 0x80008000u;
                a.x ^= FL; a.y ^= FL; a.z ^= FL; a.w ^= FL;
                b2.x ^= FL; b2.y ^= FL; b2.z ^= FL; b2.w ^= FL;
                const size_t so = base0 + (size_t)c * 4096 + qr * 64 + qc;
                *(uint4*)(Scg + so) = a;
                *(uint4*)(Scg + so + 8) = b2;
            }

            f32x4 y[4];
#pragma unroll
            for (int st = 0; st < 4; st++) {
                ushort4 vv = *(const ushort4*)&VTC[(16 * w + r15) * P72 + st * 16 + kg * 4];
                y[st][0] = bf2f(vv.x); y[st][1] = bf2f(vv.y);
                y[st][2] = bf2f(vv.z); y[st][3] = bf2f(vv.w);
            }
#pragma unroll
            for (int ks = 0; ks < 2; ks++) {
                short8 bfr = *(const short8*)&Sbf[(16 * w + r15) * P72 + ks * 32 + kg * 8];
#pragma unroll
                for (int st = 0; st < 4; st++) {
                    short8 afr = *(const short8*)&KsC[(st * 16 + r15) * P72 + ks * 32 + kg * 8];
                    y[st] = __builtin_amdgcn_mfma_f32_16x16x32_bf16(afr, bfr, y[st], 0, 0, 0);
                }
            }

#pragma unroll
            for (int b = 0; b < 4; b++) {
                if (b > 0) {
                    WAVE_SYNC();
                    f32x4 corr = {};
                    {
                        short8 afr = *(const short8*)&A0C[(b * 16 + r15) * P72 + kg * 8];
                        short8 bfr = *(const short8*)&UTs[(16 * w + r15) * P72 + kg * 8];
                        corr = __builtin_amdgcn_mfma_f32_16x16x32_bf16(afr, bfr, corr, 0, 0, 0);
                    }
                    if (b == 3) {
                        short8 afr = *(const short8*)&A0C[(b * 16 + r15) * P72 + 32 + kg * 8];
                        short8 bfr = *(const short8*)&UTs[(16 * w + r15) * P72 + 32 + kg * 8];
                        corr = __builtin_amdgcn_mfma_f32_16x16x32_bf16(afr, bfr, corr, 0, 0, 0);
                    }
                    y[b] = y[b] - corr;
                }
                ushort4 bt4 = *(const ushort4*)&BTC[(16 * w + r15) * P72 + b * 16 + kg * 4];
                const float bta0 = bf2f(bt4.x), bta1 = bf2f(bt4.y);
                const float bta2 = bf2f(bt4.z), bta3 = bf2f(bt4.w);
                float us0 = 0.f, us1 = 0.f, us2 = 0.f, us3 = 0.f;
#pragma unroll
                for (int own = 0; own < 4; own++) {
                    const f32x4 c40 = *(const f32x4*)&A0DC[(b * 16 + own * 4 + 0) * 20 + kg * 4];
                    const f32x4 c41 = *(const f32x4*)&A0DC[(b * 16 + own * 4 + 1) * 20 + kg * 4];
                    const f32x4 c42 = *(const f32x4*)&A0DC[(b * 16 + own * 4 + 2) * 20 + kg * 4];
                    const f32x4 c43 = *(const f32x4*)&A0DC[(b * 16 + own * 4 + 3) * 20 + kg * 4];
                    if (kg == own) {
                        us0 = bta0 * y[b][0];
                        us1 = bta1 * (y[b][1] - c40[1] * us0);
                        us2 = bta2 * (y[b][2] - c40[2] * us0 - c41[2] * us1);
                        us3 = bta3 * (y[b][3] - c40[3] * us0 - c41[3] * us1 - c42[3] * us2);
                    }
                    const int src = own * 16 + r15;
                    const float u0 = __shfl(us0, src), u1 = __shfl(us1, src);
                    const float u2 = __shfl(us2, src), u3 = __shfl(us3, src);
                    if (kg > own)
                        y[b] = y[b] - (c40 * u0 + c41 * u1 + c42 * u2 + c43 * u3);
                }
                ushort4 up;
                up.x = f2bf(us0); up.y = f2bf(us1); up.z = f2bf(us2); up.w = f2bf(us3);
                *(ushort4*)&UTs[(16 * w + r15) * P72 + b * 16 + kg * 4] = up;
            }
            WAVE_SYNC();

            {
                uint4 a = *(const uint4*)&UTs[qr * P72 + qc];
                uint4 b2 = *(const uint4*)&UTs[qr * P72 + qc + 8];
                const size_t so = base0 + (size_t)c * 4096 + qr * 64 + qc;
                *(uint4*)(UTg + so) = a;
                *(uint4*)(UTg + so + 8) = b2;
            }

#pragma unroll
            for (int ks = 0; ks < 2; ks++) {
                short8 afr = *(const short8*)&UTs[(16 * w + r15) * P72 + ks * 32 + kg * 8];
#pragma unroll
                for (int n = 0; n < 4; n++) {
                    short8 bfr = *(const short8*)&KTsC[(n * 16 + r15) * P72 + ks * 32 + kg * 8];
                    Sreg[n] = __builtin_amdgcn_mfma_f32_16x16x32_bf16(afr, bfr, Sreg[n], 0, 0, 0);
                }
            }
#pragma unroll
            for (int n = 0; n < 4; n++)
#pragma unroll
                for (int jj = 0; jj < 4; jj++)
                    Sbf[(16 * w + kg * 4 + jj) * P72 + n * 16 + r15] = f2bf(-Sreg[n][jj]);

            if (c < 31) {
                *(uint4*)&sK [nxt * 4608 + sr * P72 + sc] = g[0]; *(uint4*)&sK [nxt * 4608 + sr * P72 + sc + 8] = g[1];
                *(uint4*)&sKT[nxt * 4608 + sr * P72 + sc] = g[2]; *(uint4*)&sKT[nxt * 4608 + sr * P72 + sc + 8] = g[3];
                *(uint4*)&sA0[nxt * 4608 + sr * P72 + sc] = g[4]; *(uint4*)&sA0[nxt * 4608 + sr * P72 + sc + 8] = g[5];
                *(uint4*)&sVT[nxt * 4608 + sr * P72 + sc] = g[6]; *(uint4*)&sVT[nxt * 4608 + sr * P72 + sc + 8] = g[7];
                *(uint4*)&sBT[nxt * 4608 + sr * P72 + sc] = g[8]; *(uint4*)&sBT[nxt * 4608 + sr * P72 + sc + 8] = g[9];
                *(float4*)&sA0D[nxt * 1280 + dOff] = gD;
            }
        }
    } else if (blockIdx.x < 64 + 512) {
        // ======== Q-GEMM: NORM[8192][1024] x WQT[0:1024][1024]^T -> qo ========
        unsigned short* SMEM = us;
        const int blk = blockIdx.x - 64;
        // L2-grouped XCD mapping: xcd = blk&7 (HW round-robin; 64 scan blocks = 8 full
        // rounds so alignment is preserved), M-major within XCD: each XCD owns
        // 8 M-panels x 8 N-tiles; A-panel (256KB) reused by 8 consecutive blocks,
        // B (WQT 2.1MB) L2-resident.
        const int id2 = (blk & 7) * 64 + (blk >> 3);
        const int M0 = (id2 >> 3) * 128, N0 = (id2 & 7) * 128;
        const int K = 1024;
        const int lane = tid & 63;
        const int w = tid >> 6, wr = w >> 1, wc = w & 1;
        const int r15 = lane & 15, kg = lane >> 4;
        const int lr = lane >> 2, lc = (lane & 3) * 8;

        const unsigned short* Arow0 = NORM + (size_t)(M0 + w * 16 + lr) * K + lc;
        const unsigned short* Arow1 = NORM + (size_t)(M0 + 64 + w * 16 + lr) * K + lc;
        const unsigned short* Brow0 = WQT + (size_t)(N0 + w * 16 + lr) * K + lc;
        const unsigned short* Brow1 = WQT + (size_t)(N0 + 64 + w * 16 + lr) * K + lc;

        f32x4 acc[4][4] = {};

        ASYNC16(Arow0, &SMEM[(w * 16) * 32]);
        ASYNC16(Arow1, &SMEM[(64 + w * 16) * 32]);
        ASYNC16(Brow0, &SMEM[8192 + (w * 16) * 32]);
        ASYNC16(Brow1, &SMEM[8192 + (64 + w * 16) * 32]);

        int cur = 0;
        for (int k0 = 0; k0 < K; k0 += 32) {
            if (k0 + 32 < K) {
                const int nb = (cur ^ 1) * 4096;
                ASYNC16(Arow0 + k0 + 32, &SMEM[nb + (w * 16) * 32]);
                ASYNC16(Arow1 + k0 + 32, &SMEM[nb + (64 + w * 16) * 32]);
                ASYNC16(Brow0 + k0 + 32, &SMEM[8192 + nb + (w * 16) * 32]);
                ASYNC16(Brow1 + k0 + 32, &SMEM[8192 + nb + (64 + w * 16) * 32]);
                __asm__ volatile("s_waitcnt vmcnt(4)" ::: "memory");
            } else {
                __asm__ volatile("s_waitcnt vmcnt(0)" ::: "memory");
            }
            __builtin_amdgcn_s_barrier();
            __builtin_amdgcn_sched_barrier(0);
            const int cb = cur * 4096;
            short8 af[4], bf[4];
#pragma unroll
            for (int m = 0; m < 4; m++)
                af[m] = *(const short8*)&SMEM[cb + (wr * 64 + m * 16 + r15) * 32 + kg * 8];
#pragma unroll
            for (int n = 0; n < 4; n++)
                bf[n] = *(const short8*)&SMEM[8192 + cb + (wc * 64 + n * 16 + r15) * 32 + kg * 8];
#pragma unroll
            for (int m = 0; m < 4; m++)
#pragma unroll
                for (int n = 0; n < 4; n++)
                    acc[m][n] = __builtin_amdgcn_mfma_f32_16x16x32_bf16(af[m], bf[n], acc[m][n], 0, 0, 0);
            __builtin_amdgcn_sched_barrier(0);
            __builtin_amdgcn_s_barrier();
            cur ^= 1;
        }

        float bias_r[4];
#pragma unroll
        for (int n = 0; n < 4; n++) bias_r[n] = bias[N0 + wc * 64 + n * 16 + r15];
        const int hA = N0 >> 6;
#pragma unroll
        for (int p = 0; p < 2; ++p) {
            __syncthreads();
            if (wr == p) {
#pragma unroll
                for (int m = 0; m < 4; m++)
#pragma unroll
                    for (int n = 0; n < 4; n++)
#pragma unroll
                        for (int j = 0; j < 4; j++)
                            SMEM[(m * 16 + kg * 4 + j) * 136 + wc * 64 + n * 16 + r15] =
                                f2bf(acc[m][n][j] + bias_r[n]);
            }
            __syncthreads();
            const int tl = tid >> 2, sg = tid & 3;
            const int gm = M0 + p * 64 + tl;
            const int b = gm >> 11, t = gm & 2047;
            const int h = hA + (sg >> 1), d0 = (sg & 1) * 32;
            const int colbase = sg * 32;
            const size_t dst = ((size_t)(b * 16 + h) * 2048 + t) * 64 + d0;
#pragma unroll
            for (int i = 0; i < 4; i++) {
                uint4 v = *(const uint4*)&SMEM[tl * 136 + colbase + i * 8];
                *(uint4*)(qo + dst + i * 8) = v;
            }
        }
    } else {
        // ======== w_out transpose: f32 [1024][1024] -> bf16 ^T ========
        float* tile = (float*)POOL;   // [32][33]
        const int blk = blockIdx.x - 64 - 512;
        const int c0 = (blk & 31) * 32, r0 = (blk >> 5) * 32;
        const int tx = tid & 31, ty = tid >> 5;
#pragma unroll
        for (int yy = 0; yy < 32; yy += 8)
            tile[(ty + yy) * 33 + tx] = w_out[(size_t)(r0 + ty + yy) * 1024 + c0 + tx];
        __syncthreads();
#pragma unroll
        for (int yy = 0; yy < 32; yy += 8)
            WOT[(size_t)(c0 + ty + yy) * 1024 + r0 + tx] = f2bf(tile[tx * 33 + ty + yy]);
    }
}

// ---------- O kernel: O = Q S_c^T + tril(Q K^T) U'  -> ATTN bf16 ----------
__global__ __launch_bounds__(256) void out_kernel(
    const unsigned short* __restrict__ Qb, const unsigned short* __restrict__ Kb,
    const unsigned short* __restrict__ Scg, const unsigned short* __restrict__ UTg,
    unsigned short* __restrict__ attn)
{
    __shared__ __align__(16) unsigned short Qs[64 * P72];
    __shared__ __align__(16) unsigned short Kbs[64 * P72];
    __shared__ __align__(16) unsigned short Scs[64 * P72];
    __shared__ __align__(16) unsigned short UTss[64 * P72];
    __shared__ __align__(16) unsigned short Ms[64 * P72];
    __shared__ __align__(16) unsigned short Osb[64 * P72];
    const int blk = blockIdx.x, tid = threadIdx.x;
    const int bh = blk >> 5, cc = blk & 31;
    const size_t gbase = (size_t)blk * 4096;
    const int lane = tid & 63, w = tid >> 6;
    const int r15 = lane & 15, kg = lane >> 4;
    {
        const int r0 = tid >> 2, c0 = (tid & 3) * 16;
        uint4 q0 = *(const uint4*)(Qb + gbase + r0 * 64 + c0),  q1 = *(const uint4*)(Qb + gbase + r0 * 64 + c0 + 8);
        uint4 k0 = *(const uint4*)(Kb + gbase + r0 * 64 + c0),  k1 = *(const uint4*)(Kb + gbase + r0 * 64 + c0 + 8);
        uint4 s0 = *(const uint4*)(Scg + gbase + r0 * 64 + c0), s1 = *(const uint4*)(Scg + gbase + r0 * 64 + c0 + 8);
        uint4 u0 = *(const uint4*)(UTg + gbase + r0 * 64 + c0), u1 = *(const uint4*)(UTg + gbase + r0 * 64 + c0 + 8);
        *(uint4*)&Qs [r0 * P72 + c0] = q0; *(uint4*)&Qs [r0 * P72 + c0 + 8] = q1;
        *(uint4*)&Kbs[r0 * P72 + c0] = k0; *(uint4*)&Kbs[r0 * P72 + c0 + 8] = k1;
        *(uint4*)&Scs[r0 * P72 + c0] = s0; *(uint4*)&Scs[r0 * P72 + c0 + 8] = s1;
        *(uint4*)&UTss[r0 * P72 + c0] = u0; *(uint4*)&UTss[r0 * P72 + c0 + 8] = u1;
    }
    __syncthreads();
    {
        f32x4 accm[4] = {{0,0,0,0},{0,0,0,0},{0,0,0,0},{0,0,0,0}};
#pragma unroll
        for (int ks = 0; ks < 2; ks++) {
            short8 afr = *(const short8*)&Qs[(w * 16 + r15) * P72 + ks * 32 + kg * 8];
#pragma unroll
            for (int n = 0; n < 4; n++) {
                short8 bfr = *(const short8*)&Kbs[(n * 16 + r15) * P72 + ks * 32 + kg * 8];
                accm[n] = __builtin_amdgcn_mfma_f32_16x16x32_bf16(afr, bfr, accm[n], 0, 0, 0);
            }
        }
#pragma unroll
        for (int n = 0; n < 4; n++)
#pragma unroll
            for (int j = 0; j < 4; j++) {
                const int t = w * 16 + kg * 4 + j, s = n * 16 + r15;
                Ms[t * P72 + s] = (s <= t) ? f2bf(accm[n][j]) : (unsigned short)0;
            }
    }
    __syncthreads();
    {
        f32x4 acc[4] = {{0,0,0,0},{0,0,0,0},{0,0,0,0},{0,0,0,0}};
#pragma unroll
        for (int ks = 0; ks < 2; ks++) {
            short8 afr = *(const short8*)&Qs[(w * 16 + r15) * P72 + ks * 32 + kg * 8];
#pragma unroll
            for (int n = 0; n < 4; n++) {
                short8 bfr = *(const short8*)&Scs[(n * 16 + r15) * P72 + ks * 32 + kg * 8];
                acc[n] = __builtin_amdgcn_mfma_f32_16x16x32_bf16(afr, bfr, acc[n], 0, 0, 0);
            }
        }
#pragma unroll
        for (int ks = 0; ks < 2; ks++) {
            short8 afr = *(const short8*)&Ms[(w * 16 + r15) * P72 + ks * 32 + kg * 8];
#pragma unroll
            for (int n = 0; n < 4; n++) {
                short8 bfr = *(const short8*)&UTss[(n * 16 + r15) * P72 + ks * 32 + kg * 8];
                acc[n] = __builtin_amdgcn_mfma_f32_16x16x32_bf16(afr, bfr, acc[n], 0, 0, 0);
            }
        }
#pragma unroll
        for (int n = 0; n < 4; n++)
#pragma unroll
            for (int j = 0; j < 4; j++) {
                const int t = w * 16 + kg * 4 + j, i = n * 16 + r15;
                Osb[t * P72 + i] = f2bf(acc[n][j]);
            }
    }
    __syncthreads();
    {
        const int b = bh >> 4, h = bh & 15;
        const int t = tid >> 2, i0 = (tid & 3) * 16;
        uint4 o0 = *(const uint4*)&Osb[t * P72 + i0];
        uint4 o1 = *(const uint4*)&Osb[t * P72 + i0 + 8];
        unsigned short* dst = attn + ((size_t)(b * 2048 + cc * 64 + t)) * 1024 + h * 64 + i0;
        *(uint4*)dst = o0;
        *(uint4*)(dst + 8) = o1;
    }
}

// ---------- launch ----------
extern "C" void kernel_launch(void* const* d_in, const int* in_sizes, int n_in,
                              void* d_out, int out_size, void* d_ws, size_t ws_size,
                              hipStream_t stream)
{
    const float* x      = (const float*)d_in[0];
    const float* ln_g   = (const float*)d_in[1];
    const float* ln_b   = (const float*)d_in[2];
    const float* w_qkvb = (const float*)d_in[3];
    const float* b_qkvb = (const float*)d_in[4];
    const float* w_out  = (const float*)d_in[5];
    const float* b_out  = (const float*)d_in[6];
    float* out = (float*)d_out;

    char* ws = (char*)d_ws;
    size_t off = 0;
    auto alloc = [&](size_t bytes) -> char* {
        char* p = ws + off;
        off = (off + bytes + 255) & ~(size_t)255;
        return p;
    };
    const size_t TOK = 64ull * 2048 * 64;
    unsigned short* WQT  = (unsigned short*)alloc(4096ull * 1024 * 2);
    unsigned short* WOT  = (unsigned short*)alloc(1024ull * 1024 * 2);
    unsigned short* NORM = (unsigned short*)alloc(TOK * 2 * 2);
    unsigned short* Qb   = (unsigned short*)alloc(TOK * 2);
    unsigned short* Kpre = (unsigned short*)alloc(TOK * 2);
    unsigned short* Kb   = (unsigned short*)alloc(TOK * 2);
    unsigned short* KTb  = (unsigned short*)alloc(TOK * 2);
    unsigned short* Vb   = (unsigned short*)alloc(TOK * 2);
    unsigned short* Bb   = (unsigned short*)alloc(TOK * 2);
    unsigned short* A0   = (unsigned short*)alloc(TOK * 2);
    unsigned short* Sc   = (unsigned short*)alloc(TOK * 2);
    unsigned short* UT   = (unsigned short*)alloc(TOK * 2);
    float*          A0D  = (float*)alloc(2048ull * 1024 * 4);
    unsigned short* ATTN = NORM;   // NORM dead after fused (Q-GEMM reads it there)
    unsigned short* VTb  = Vb;     // prep transposes in place (per-block disjoint r/w)
    unsigned short* BTb  = Bb;

    hipLaunchKernelGGL(ln_wqt_kernel, dim3(8192 + 4096), dim3(256), 0, stream,
                       x, ln_g, ln_b, NORM, w_qkvb, WQT);
    // gemm1a: K,V,beta only (cols 1024..4095) — 256x128 phase-interleaved kernel
    hipLaunchKernelGGL(gemm256, dim3(24, 32), dim3(512), 0, stream,
                       NORM, WQT, b_qkvb, 1024, 1024, Qb, Kpre, Vb, Bb);
    hipLaunchKernelGGL(prep_kernel, dim3(2048), dim3(256), 0, stream,
                       Kpre, Vb, Bb, Kb, A0, A0D, KTb, VTb, BTb);
    // fused: scan (64) | Q-GEMM (512) | w_out transpose (1024)
    hipLaunchKernelGGL(fused_scan_kernel, dim3(64 + 512 + 1024), dim3(256), 0, stream,
                       A0, Kb, KTb, A0D, VTb, BTb, Sc, UT,
                       NORM, WQT, b_qkvb, Qb, w_out, WOT);
    hipLaunchKernelGGL(out_kernel, dim3(2048), dim3(256), 0, stream, Qb, Kb, Sc, UT, ATTN);
    hipLaunchKernelGGL(gemm128, dim3(8, 64), dim3(256), 0, stream,
                       ATTN, WOT, b_out, 1024, 1024, 1, 0,
                       x, out, (unsigned short*)nullptr, (unsigned short*)nullptr,
                       (unsigned short*)nullptr, (unsigned short*)nullptr);
}